// Round 1
// baseline (284.376 us; speedup 1.0000x reference)
//
#include <hip/hip_runtime.h>
#include <hip/hip_bf16.h>
#include <stdint.h>

#define S_LEN 4096

typedef short s16x8  __attribute__((ext_vector_type(8)));
typedef float f32x4  __attribute__((ext_vector_type(4)));
typedef float f32x16 __attribute__((ext_vector_type(16)));

// log2(e)/8 : folded into Q at QKV epilogue; attn does exp2(score) directly
#define CEXP 0.18033688011112042f

__device__ __forceinline__ unsigned short f2bf(float f) {
    union { float f; unsigned u; } v; v.f = f;
    unsigned r = v.u + 0x7fffu + ((v.u >> 16) & 1u);
    return (unsigned short)(r >> 16);
}

__device__ __forceinline__ ushort2 pkbf(float a, float b) {
    float2 f; f.x = a; f.y = b;
    __hip_bfloat162 h = __float22bfloat162_rn(f);
    union { __hip_bfloat162 h; ushort2 u; } cv; cv.h = h;
    return cv.u;
}

__device__ __forceinline__ ushort4 pkbf4(float x, float y, float z, float w) {
    ushort2 lo = pkbf(x, y), hi = pkbf(z, w);
    ushort4 r; r.x = lo.x; r.y = lo.y; r.z = hi.x; r.w = hi.y;
    return r;
}

__device__ __forceinline__ unsigned pku(float a, float b) {
    union { ushort2 s; unsigned u; } c; c.s = pkbf(a, b); return c.u;
}

typedef const __attribute__((address_space(1))) void* gas_t;
typedef __attribute__((address_space(3))) void* sas_t;

__device__ __forceinline__ void async16(const void* g, void* s) {
    __builtin_amdgcn_global_load_lds((gas_t)g, (sas_t)s, 16, 0, 0);
}

// ---------------------------------------------------------------------------
// fp32 -> bf16 convert for X (4194304) and W (3145728). 8 elems/thread.
// ---------------------------------------------------------------------------
__global__ __launch_bounds__(256) void cvt_bf16(
    const float* __restrict__ X, const float* __restrict__ W,
    unsigned short* __restrict__ Xb, unsigned short* __restrict__ Wb)
{
    const long NX = 4194304;
    long i = (long)(blockIdx.x * 256 + threadIdx.x) * 8;
    const float* src; unsigned short* dst; long off;
    if (i < NX) { src = X; dst = Xb; off = i; }
    else        { src = W; dst = Wb; off = i - NX; }
    float4 a = *(const float4*)(src + off);
    float4 b = *(const float4*)(src + off + 4);
    union { s16x8 v; ushort4 q[2]; } o;
    o.q[0] = pkbf4(a.x, a.y, a.z, a.w);
    o.q[1] = pkbf4(b.x, b.y, b.z, b.w);
    *(s16x8*)(dst + off) = o.v;
}

// ---------------------------------------------------------------------------
// Kernel A (primary): qkv = Xb @ Wb^T + b, bf16 in, m97-style staging.
// (unchanged this round)
// ---------------------------------------------------------------------------
__global__ __launch_bounds__(256) void qkv_gemm_bf16(
    const unsigned short* __restrict__ Xb, const unsigned short* __restrict__ Wb,
    const float* __restrict__ bias, const float* __restrict__ trace,
    unsigned short* __restrict__ Qb, unsigned short* __restrict__ Kb,
    unsigned short* __restrict__ Vt)
{
    __shared__ __align__(16) unsigned short sm[17408];   // 34816 B
    unsigned short* As = sm;            // [128][64] bf16, unpadded (async dst)
    unsigned short* Bs = sm + 8192;     // [128][64]

    const int t = threadIdx.x;
    const int l = t & 63;
    const int w = t >> 6;
    const int bm = blockIdx.y, bn = blockIdx.x;
    const int rowBase = (w >> 1) * 64;
    const int colBase = (w & 1) * 64;

    f32x4 acc[4][4];
#pragma unroll
    for (int i = 0; i < 4; i++)
#pragma unroll
        for (int j = 0; j < 4; j++) acc[i][j] = (f32x4)0.f;

    const int srow = l >> 3;        // 0..7
    const int scol = (l & 7) * 8;   // shorts

    for (int kt = 0; kt < 16; ++kt) {
        const int k0 = kt * 64;
#pragma unroll
        for (int c = 0; c < 4; ++c) {
            int m = w * 4 + c;                    // chunk 0..15 (8 rows each)
            const unsigned short* ga = Xb + (bm * 128 + m * 8 + srow) * 1024 + k0 + scol;
            const unsigned short* gb = Wb + (bn * 128 + m * 8 + srow) * 1024 + k0 + scol;
            async16(ga, As + m * 512);
            async16(gb, Bs + m * 512);
        }
        __syncthreads();

#pragma unroll
        for (int kc = 0; kc < 2; ++kc) {
            s16x8 af[4], bf[4];
#pragma unroll
            for (int i = 0; i < 4; i++) {
                af[i] = *(const s16x8*)(As + (rowBase + i * 16 + (l & 15)) * 64 + kc * 32 + (l >> 4) * 8);
                bf[i] = *(const s16x8*)(Bs + (colBase + i * 16 + (l & 15)) * 64 + kc * 32 + (l >> 4) * 8);
            }
#pragma unroll
            for (int i = 0; i < 4; i++)
#pragma unroll
                for (int j = 0; j < 4; j++)
                    acc[i][j] = __builtin_amdgcn_mfma_f32_16x16x32_bf16(af[i], bf[j], acc[i][j], 0, 0, 0);
        }
        __syncthreads();
    }

    if (bn < 16) {
#pragma unroll
        for (int j = 0; j < 4; j++) {
            int col = bn * 128 + colBase + j * 16 + (l & 15);
            float bv = bias[col];
            int region = col >> 10;            // 0=Q, 1=K
            int within = col & 1023;
            int h = within >> 6, d = within & 63;
            unsigned short* dst = (region == 0) ? Qb : Kb;
            float scl = (region == 0) ? CEXP : 1.0f;
#pragma unroll
            for (int i = 0; i < 4; i++) {
                int s0 = bm * 128 + rowBase + i * 16 + ((l >> 4) << 2);
#pragma unroll
                for (int r = 0; r < 4; r++)
                    dst[(h * S_LEN + s0 + r) * 64 + d] = f2bf((acc[i][j][r] + bv) * scl);
            }
        }
    } else {
        __syncthreads();
        unsigned short* Lt = sm;              // 128 x 136
#pragma unroll
        for (int j = 0; j < 4; j++) {
            int cl = colBase + j * 16 + (l & 15);
            int o  = bn * 128 + cl - 2048;     // 0..1023 within V
            float bv = bias[bn * 128 + cl];
            float tr = trace[(o >> 6) * 4096 + (o & 63) * 65];
#pragma unroll
            for (int i = 0; i < 4; i++) {
                int s0 = rowBase + i * 16 + ((l >> 4) << 2);
                *(ushort4*)(Lt + cl * 136 + s0) =
                    pkbf4((acc[i][j][0] + bv) * tr, (acc[i][j][1] + bv) * tr,
                          (acc[i][j][2] + bv) * tr, (acc[i][j][3] + bv) * tr);
            }
        }
        __syncthreads();
#pragma unroll
        for (int p = 0; p < 8; ++p) {
            int dl  = (t >> 4) + p * 16;
            int sch = (t & 15) * 8;
            int o = bn * 128 + dl - 2048;
            int h = o >> 6, d = o & 63;
            s16x8 v = *(const s16x8*)(Lt + dl * 136 + sch);
            *(s16x8*)(Vt + (h * 64 + d) * S_LEN + bm * 128 + sch) = v;
        }
    }
}

// ---------------------------------------------------------------------------
// Kernel A (fallback, small ws): fp32-staged GEMM, same outputs
// ---------------------------------------------------------------------------
__global__ __launch_bounds__(256) void qkv_gemm_f32(
    const float* __restrict__ X, const float* __restrict__ W,
    const float* __restrict__ bias, const float* __restrict__ trace,
    unsigned short* __restrict__ Qb, unsigned short* __restrict__ Kb,
    unsigned short* __restrict__ Vt)
{
    __shared__ __align__(16) unsigned short sm[17408];
    unsigned short* As = sm;
    unsigned short* Bs = sm + 5120;

    const int t = threadIdx.x;
    const int l = t & 63;
    const int w = t >> 6;
    const int bm = blockIdx.y, bn = blockIdx.x;
    const int rowBase = (w >> 1) * 64;
    const int colBase = (w & 1) * 64;

    f32x4 acc[4][4];
#pragma unroll
    for (int i = 0; i < 4; i++)
#pragma unroll
        for (int j = 0; j < 4; j++) acc[i][j] = (f32x4)0.f;

    const int sr = t >> 3;
    const int sc = (t & 7) * 4;

    for (int kt = 0; kt < 32; ++kt) {
        const int k0 = kt * 32;
#pragma unroll
        for (int p = 0; p < 4; ++p) {
            int r = sr + p * 32;
            float4 xa = *(const float4*)(X + (bm * 128 + r) * 1024 + k0 + sc);
            float4 wb = *(const float4*)(W + (bn * 128 + r) * 1024 + k0 + sc);
            *(ushort4*)(As + r * 40 + sc) = pkbf4(xa.x, xa.y, xa.z, xa.w);
            *(ushort4*)(Bs + r * 40 + sc) = pkbf4(wb.x, wb.y, wb.z, wb.w);
        }
        __syncthreads();

        s16x8 af[4], bf[4];
#pragma unroll
        for (int i = 0; i < 4; i++) {
            af[i] = *(const s16x8*)(As + (rowBase + i * 16 + (l & 15)) * 40 + (l >> 4) * 8);
            bf[i] = *(const s16x8*)(Bs + (colBase + i * 16 + (l & 15)) * 40 + (l >> 4) * 8);
        }
#pragma unroll
        for (int i = 0; i < 4; i++)
#pragma unroll
            for (int j = 0; j < 4; j++)
                acc[i][j] = __builtin_amdgcn_mfma_f32_16x16x32_bf16(af[i], bf[j], acc[i][j], 0, 0, 0);
        __syncthreads();
    }

    if (bn < 16) {
#pragma unroll
        for (int j = 0; j < 4; j++) {
            int col = bn * 128 + colBase + j * 16 + (l & 15);
            float bv = bias[col];
            int region = col >> 10;
            int within = col & 1023;
            int h = within >> 6, d = within & 63;
            unsigned short* dst = (region == 0) ? Qb : Kb;
            float scl = (region == 0) ? CEXP : 1.0f;
#pragma unroll
            for (int i = 0; i < 4; i++) {
                int s0 = bm * 128 + rowBase + i * 16 + ((l >> 4) << 2);
#pragma unroll
                for (int r = 0; r < 4; r++)
                    dst[(h * S_LEN + s0 + r) * 64 + d] = f2bf((acc[i][j][r] + bv) * scl);
            }
        }
    } else {
        __syncthreads();
        unsigned short* Lt = sm;
#pragma unroll
        for (int j = 0; j < 4; j++) {
            int cl = colBase + j * 16 + (l & 15);
            int o  = bn * 128 + cl - 2048;
            float bv = bias[bn * 128 + cl];
            float tr = trace[(o >> 6) * 4096 + (o & 63) * 65];
#pragma unroll
            for (int i = 0; i < 4; i++) {
                int s0 = rowBase + i * 16 + ((l >> 4) << 2);
                *(ushort4*)(Lt + cl * 136 + s0) =
                    pkbf4((acc[i][j][0] + bv) * tr, (acc[i][j][1] + bv) * tr,
                          (acc[i][j][2] + bv) * tr, (acc[i][j][3] + bv) * tr);
            }
        }
        __syncthreads();
#pragma unroll
        for (int p = 0; p < 8; ++p) {
            int dl  = (t >> 4) + p * 16;
            int sch = (t & 15) * 8;
            int o = bn * 128 + dl - 2048;
            int h = o >> 6, d = o & 63;
            s16x8 v = *(const s16x8*)(Lt + dl * 136 + sch);
            *(s16x8*)(Vt + (h * 64 + d) * S_LEN + bm * 128 + sch) = v;
        }
    }
}

// ---------------------------------------------------------------------------
// Kernel B: flash attention. Changes this round (vs 212.7 µs version):
//  1. T12: P never touches LDS. After S^T = K·Q^T (32x32x16), lane holds
//     P[kv=(r&3)+8*(r>>2)+4*lh][q=l31]. The PV B-fragment needs
//     P[kv=ks*16+lh*8+e][q=l31]: pairs {r,r+1} and {r+4,r+5} cvt_pk'd and
//     exchanged with v_permlane32_swap (D.row1<->S.row0) give exactly the
//     four dwords of the fragment. Removes the 34KB Pw region + 16 LDS
//     ops/kt/wave off the critical path.
//  2. T14 + double-buffered K/V: one barrier per kt. Global loads for kt+1
//     issue right after the barrier; ds_writes land at the bottom of the
//     iteration (vmcnt waited there, hidden under QK/softmax/PV).
//  3. T5: s_setprio(1) around both MFMA clusters.
// LDS: 2 bufs x 2 groups x 9216 shorts = 73728 B (+1KB lArr) -> still
// 2 blocks/CU (grid=512 is 2/CU anyway, occupancy is grid-quantized).
// ---------------------------------------------------------------------------
__global__ __launch_bounds__(512, 4) void attn(
    const unsigned short* __restrict__ Qb, const unsigned short* __restrict__ Kb,
    const unsigned short* __restrict__ Vt, float* __restrict__ out)
{
    __shared__ __align__(16) unsigned short sm[36864];   // 73728 B: [buf][group][K|V]
    __shared__ float lArr[256];

    const int t = threadIdx.x;
    const int l = t & 63;
    const int w = t >> 6;            // 0..7
    const int g = w >> 2;            // kv half
    const int wq = w & 3;            // q sub-tile
    // XCD swizzle: xcd = bid%8 owns heads {2*xcd, 2*xcd+1}
    const int bid = blockIdx.x;
    const int xcd = bid & 7;
    const int j   = bid >> 3;        // 0..63
    const int h   = xcd * 2 + (j & 1);
    const int qblk = j >> 1;         // 0..31
    const int qbase = qblk * 128 + wq * 32;
    const int l31 = l & 31;
    const int lh  = l >> 5;

    s16x8 qf[4];
#pragma unroll
    for (int ks = 0; ks < 4; ks++)
        qf[ks] = *(const s16x8*)(Qb + (h * S_LEN + qbase + l31) * 64 + ks * 16 + lh * 8);

    f32x16 O0 = (f32x16)0.f, O1 = (f32x16)0.f;
    float2 lpA; lpA.x = 0.f; lpA.y = 0.f;
    float2 lpB; lpB.x = 0.f; lpB.y = 0.f;

    const int tg    = t & 255;           // position within group
    const int strow = tg >> 2;           // 0..63
    const int stch  = (tg & 3) * 16;

    // group-g staging pointers, kt=0
    const unsigned short* kp = Kb + (h * S_LEN + g * 2048 + strow) * 64 + stch;
    const unsigned short* vp = Vt + (h * 64 + strow) * S_LEN + g * 2048 + stch;

    // prologue: stage tile 0 into buf 0
    s16x8 rk0 = *(const s16x8*)(kp);
    s16x8 rk1 = *(const s16x8*)(kp + 8);
    s16x8 rv0 = *(const s16x8*)(vp);
    s16x8 rv1 = *(const s16x8*)(vp + 8);
    {
        unsigned short* K0 = sm + g * 9216;
        *(s16x8*)(K0 + strow * 72 + stch)          = rk0;
        *(s16x8*)(K0 + strow * 72 + stch + 8)      = rk1;
        *(s16x8*)(K0 + 4608 + strow * 72 + stch)     = rv0;
        *(s16x8*)(K0 + 4608 + strow * 72 + stch + 8) = rv1;
    }

    for (int kt = 0; kt < 32; ++kt) {
        __syncthreads();                 // buf[kt&1] staged; buf[kt&1^1] fully drained
        const int cur = kt & 1;
        unsigned short* Ks  = sm + (cur * 2 + g) * 9216;
        unsigned short* Vts = Ks + 4608;

        // T14: issue next tile's global loads now; latency hides under compute
        if (kt < 31) {
            kp += 4096;                  // 64 kv rows x 64 d
            vp += 64;
            rk0 = *(const s16x8*)(kp);
            rk1 = *(const s16x8*)(kp + 8);
            rv0 = *(const s16x8*)(vp);
            rv1 = *(const s16x8*)(vp + 8);
        }

        // S^T[kv][q] = K x Q^T  (scores pre-scaled via Q)
        f32x16 S0 = (f32x16)0.f, S1 = (f32x16)0.f;
        __builtin_amdgcn_s_setprio(1);
#pragma unroll
        for (int ks = 0; ks < 4; ks++) {
            s16x8 a0 = *(const s16x8*)(Ks + l31 * 72 + ks * 16 + lh * 8);
            s16x8 a1 = *(const s16x8*)(Ks + (32 + l31) * 72 + ks * 16 + lh * 8);
            S0 = __builtin_amdgcn_mfma_f32_32x32x16_bf16(a0, qf[ks], S0, 0, 0, 0);
            S1 = __builtin_amdgcn_mfma_f32_32x32x16_bf16(a1, qf[ks], S1, 0, 0, 0);
        }
        __builtin_amdgcn_s_setprio(0);

#pragma unroll
        for (int i = 0; i < 16; i += 4) {
            float p0 = __builtin_amdgcn_exp2f(S0[i+0]); S0[i+0] = p0; lpA.x += p0;
            float p1 = __builtin_amdgcn_exp2f(S0[i+1]); S0[i+1] = p1; lpA.y += p1;
            float p2 = __builtin_amdgcn_exp2f(S0[i+2]); S0[i+2] = p2; lpB.x += p2;
            float p3 = __builtin_amdgcn_exp2f(S0[i+3]); S0[i+3] = p3; lpB.y += p3;
        }
#pragma unroll
        for (int i = 0; i < 16; i += 4) {
            float p0 = __builtin_amdgcn_exp2f(S1[i+0]); S1[i+0] = p0; lpA.x += p0;
            float p1 = __builtin_amdgcn_exp2f(S1[i+1]); S1[i+1] = p1; lpA.y += p1;
            float p2 = __builtin_amdgcn_exp2f(S1[i+2]); S1[i+2] = p2; lpB.x += p2;
            float p3 = __builtin_amdgcn_exp2f(S1[i+3]); S1[i+3] = p3; lpB.y += p3;
        }

        // T12: O^T[d][q] += V^T x P^T with P^T built in-register.
        // B-frag elem e (k = lh*8+e) of kv-block ks needs P[ks*16+lh*8+e][l31].
        // permlane32_swap(D,S): D' = {D.row0, S.row0}, S' = {D.row1, S.row1}.
        __builtin_amdgcn_s_setprio(1);
#pragma unroll
        for (int ks = 0; ks < 4; ks++) {
            const f32x16 Sx = (ks < 2) ? S0 : S1;
            const int b = (ks & 1) * 8;
            unsigned pa0 = pku(Sx[b+0], Sx[b+1]);   // kv {b+0,b+1 | b+4,b+5}+base
            unsigned pc0 = pku(Sx[b+4], Sx[b+5]);   // kv {b+8,b+9 | b+12,b+13}+base
            unsigned pa1 = pku(Sx[b+2], Sx[b+3]);
            unsigned pc1 = pku(Sx[b+6], Sx[b+7]);
            auto r0 = __builtin_amdgcn_permlane32_swap(pa0, pc0, false, false);
            auto r1 = __builtin_amdgcn_permlane32_swap(pa1, pc1, false, false);
            union { s16x8 v; unsigned u[4]; } pb;
            pb.u[0] = r0[0]; pb.u[1] = r1[0]; pb.u[2] = r0[1]; pb.u[3] = r1[1];
            s16x8 av0 = *(const s16x8*)(Vts + l31 * 72 + ks * 16 + lh * 8);
            s16x8 av1 = *(const s16x8*)(Vts + (32 + l31) * 72 + ks * 16 + lh * 8);
            O0 = __builtin_amdgcn_mfma_f32_32x32x16_bf16(av0, pb.v, O0, 0, 0, 0);
            O1 = __builtin_amdgcn_mfma_f32_32x32x16_bf16(av1, pb.v, O1, 0, 0, 0);
        }
        __builtin_amdgcn_s_setprio(0);

        // write next tile into the other buffer (vmcnt waited here, not at top)
        if (kt < 31) {
            unsigned short* Kn = sm + (((cur ^ 1) * 2) + g) * 9216;
            *(s16x8*)(Kn + strow * 72 + stch)          = rk0;
            *(s16x8*)(Kn + strow * 72 + stch + 8)      = rk1;
            *(s16x8*)(Kn + 4608 + strow * 72 + stch)     = rv0;
            *(s16x8*)(Kn + 4608 + strow * 72 + stch + 8) = rv1;
        }
    }

    // per-wave l partial for q = qbase + l31
    float l_part = (lpA.x + lpA.y) + (lpB.x + lpB.y);
    float l_tot = l_part + __shfl_xor(l_part, 32);
    if (lh == 0) lArr[w * 32 + l31] = l_tot;

    __syncthreads();    // drain last PV's LDS reads before Lo overwrites sm

    // stash raw O^T (fp32) per wave: Lo[w][q 0..31][d 0..67(pad)]
    float* Lo = (float*)sm + w * 2176;
#pragma unroll
    for (int dt = 0; dt < 2; ++dt) {
        const f32x16& Ox = dt ? O1 : O0;
#pragma unroll
        for (int gq = 0; gq < 4; ++gq) {
            int d0 = dt * 32 + gq * 8 + lh * 4;
            float4 vv;
            vv.x = Ox[gq*4+0]; vv.y = Ox[gq*4+1]; vv.z = Ox[gq*4+2]; vv.w = Ox[gq*4+3];
            *(float4*)(Lo + l31 * 68 + d0) = vv;
        }
    }
    __syncthreads();

    // waves 0-3: combine the two kv-half partials, normalize, store
    if (w < 4) {
        const float* LoA = (float*)sm + w * 2176;
        const float* LoB = (float*)sm + (w + 4) * 2176;
#pragma unroll
        for (int it = 0; it < 8; ++it) {
            int ql = it * 4 + (l >> 4);
            float invl = 1.0f / (lArr[w * 32 + ql] + lArr[(w + 4) * 32 + ql]);
            float4 a = *(const float4*)(LoA + ql * 68 + (l & 15) * 4);
            float4 b = *(const float4*)(LoB + ql * 68 + (l & 15) * 4);
            float4 vv;
            vv.x = (a.x + b.x) * invl;
            vv.y = (a.y + b.y) * invl;
            vv.z = (a.z + b.z) * invl;
            vv.w = (a.w + b.w) * invl;
            *(float4*)(out + (qblk * 128 + w * 32 + ql) * 1024 + h * 64 + (l & 15) * 4) = vv;
        }
    }
}

extern "C" void kernel_launch(void* const* d_in, const int* in_sizes, int n_in,
                              void* d_out, int out_size, void* d_ws, size_t ws_size,
                              hipStream_t stream) {
    const float* X     = (const float*)d_in[0];   // [1,4096,1024]
    const float* W     = (const float*)d_in[1];   // [3072,1024]
    const float* bias  = (const float*)d_in[2];   // [3072]
    const float* trace = (const float*)d_in[3];   // [16,64,64]
    float* out = (float*)d_out;

    unsigned short* Qb = (unsigned short*)d_ws;            // 8 MiB [h][s][d] (pre-scaled by CEXP)
    unsigned short* Kb = Qb + 4194304;                     // 8 MiB [h][s][d]
    unsigned short* Vt = Kb + 4194304;                     // 8 MiB [h][d][s] (pre-scaled by trace diag)
    unsigned short* Xb = Vt + 4194304;                     // 8 MiB bf16 X
    unsigned short* Wb = Xb + 4194304;                     // 6 MiB bf16 W

    const size_t NEED_BF16 = (size_t)3 * 8388608 + 8388608 + 6291456;

    if (ws_size >= NEED_BF16) {
        cvt_bf16<<<3584, 256, 0, stream>>>(X, W, Xb, Wb);
        qkv_gemm_bf16<<<dim3(24, 32), 256, 0, stream>>>(Xb, Wb, bias, trace, Qb, Kb, Vt);
    } else {
        qkv_gemm_f32<<<dim3(24, 32), 256, 0, stream>>>(X, W, bias, trace, Qb, Kb, Vt);
    }
    attn<<<512, 512, 0, stream>>>(Qb, Kb, Vt, out);
}

// Round 2
// 208.342 us; speedup vs baseline: 1.3650x; 1.3650x over previous
//
#include <hip/hip_runtime.h>
#include <hip/hip_bf16.h>
#include <stdint.h>

#define S_LEN 4096

typedef short s16x8  __attribute__((ext_vector_type(8)));
typedef float f32x4  __attribute__((ext_vector_type(4)));
typedef float f32x16 __attribute__((ext_vector_type(16)));

// log2(e)/8 : folded into Q at QKV epilogue; attn does exp2(score) directly
#define CEXP 0.18033688011112042f

__device__ __forceinline__ unsigned short f2bf(float f) {
    union { float f; unsigned u; } v; v.f = f;
    unsigned r = v.u + 0x7fffu + ((v.u >> 16) & 1u);
    return (unsigned short)(r >> 16);
}

__device__ __forceinline__ ushort2 pkbf(float a, float b) {
    float2 f; f.x = a; f.y = b;
    __hip_bfloat162 h = __float22bfloat162_rn(f);
    union { __hip_bfloat162 h; ushort2 u; } cv; cv.h = h;
    return cv.u;
}

__device__ __forceinline__ ushort4 pkbf4(float x, float y, float z, float w) {
    ushort2 lo = pkbf(x, y), hi = pkbf(z, w);
    ushort4 r; r.x = lo.x; r.y = lo.y; r.z = hi.x; r.w = hi.y;
    return r;
}

__device__ __forceinline__ unsigned pku(float a, float b) {
    union { ushort2 s; unsigned u; } c; c.s = pkbf(a, b); return c.u;
}

typedef const __attribute__((address_space(1))) void* gas_t;
typedef __attribute__((address_space(3))) void* sas_t;

__device__ __forceinline__ void async16(const void* g, void* s) {
    __builtin_amdgcn_global_load_lds((gas_t)g, (sas_t)s, 16, 0, 0);
}

// ---------------------------------------------------------------------------
// fp32 -> bf16 convert for X (4194304) and W (3145728). 8 elems/thread.
// ---------------------------------------------------------------------------
__global__ __launch_bounds__(256) void cvt_bf16(
    const float* __restrict__ X, const float* __restrict__ W,
    unsigned short* __restrict__ Xb, unsigned short* __restrict__ Wb)
{
    const long NX = 4194304;
    long i = (long)(blockIdx.x * 256 + threadIdx.x) * 8;
    const float* src; unsigned short* dst; long off;
    if (i < NX) { src = X; dst = Xb; off = i; }
    else        { src = W; dst = Wb; off = i - NX; }
    float4 a = *(const float4*)(src + off);
    float4 b = *(const float4*)(src + off + 4);
    union { s16x8 v; ushort4 q[2]; } o;
    o.q[0] = pkbf4(a.x, a.y, a.z, a.w);
    o.q[1] = pkbf4(b.x, b.y, b.z, b.w);
    *(s16x8*)(dst + off) = o.v;
}

// ---------------------------------------------------------------------------
// Kernel A (primary): qkv = Xb @ Wb^T + b, bf16 in, m97-style staging.
// (unchanged)
// ---------------------------------------------------------------------------
__global__ __launch_bounds__(256) void qkv_gemm_bf16(
    const unsigned short* __restrict__ Xb, const unsigned short* __restrict__ Wb,
    const float* __restrict__ bias, const float* __restrict__ trace,
    unsigned short* __restrict__ Qb, unsigned short* __restrict__ Kb,
    unsigned short* __restrict__ Vt)
{
    __shared__ __align__(16) unsigned short sm[17408];   // 34816 B
    unsigned short* As = sm;            // [128][64] bf16, unpadded (async dst)
    unsigned short* Bs = sm + 8192;     // [128][64]

    const int t = threadIdx.x;
    const int l = t & 63;
    const int w = t >> 6;
    const int bm = blockIdx.y, bn = blockIdx.x;
    const int rowBase = (w >> 1) * 64;
    const int colBase = (w & 1) * 64;

    f32x4 acc[4][4];
#pragma unroll
    for (int i = 0; i < 4; i++)
#pragma unroll
        for (int j = 0; j < 4; j++) acc[i][j] = (f32x4)0.f;

    const int srow = l >> 3;        // 0..7
    const int scol = (l & 7) * 8;   // shorts

    for (int kt = 0; kt < 16; ++kt) {
        const int k0 = kt * 64;
#pragma unroll
        for (int c = 0; c < 4; ++c) {
            int m = w * 4 + c;                    // chunk 0..15 (8 rows each)
            const unsigned short* ga = Xb + (bm * 128 + m * 8 + srow) * 1024 + k0 + scol;
            const unsigned short* gb = Wb + (bn * 128 + m * 8 + srow) * 1024 + k0 + scol;
            async16(ga, As + m * 512);
            async16(gb, Bs + m * 512);
        }
        __syncthreads();

#pragma unroll
        for (int kc = 0; kc < 2; ++kc) {
            s16x8 af[4], bf[4];
#pragma unroll
            for (int i = 0; i < 4; i++) {
                af[i] = *(const s16x8*)(As + (rowBase + i * 16 + (l & 15)) * 64 + kc * 32 + (l >> 4) * 8);
                bf[i] = *(const s16x8*)(Bs + (colBase + i * 16 + (l & 15)) * 64 + kc * 32 + (l >> 4) * 8);
            }
#pragma unroll
            for (int i = 0; i < 4; i++)
#pragma unroll
                for (int j = 0; j < 4; j++)
                    acc[i][j] = __builtin_amdgcn_mfma_f32_16x16x32_bf16(af[i], bf[j], acc[i][j], 0, 0, 0);
        }
        __syncthreads();
    }

    if (bn < 16) {
#pragma unroll
        for (int j = 0; j < 4; j++) {
            int col = bn * 128 + colBase + j * 16 + (l & 15);
            float bv = bias[col];
            int region = col >> 10;            // 0=Q, 1=K
            int within = col & 1023;
            int h = within >> 6, d = within & 63;
            unsigned short* dst = (region == 0) ? Qb : Kb;
            float scl = (region == 0) ? CEXP : 1.0f;
#pragma unroll
            for (int i = 0; i < 4; i++) {
                int s0 = bm * 128 + rowBase + i * 16 + ((l >> 4) << 2);
#pragma unroll
                for (int r = 0; r < 4; r++)
                    dst[(h * S_LEN + s0 + r) * 64 + d] = f2bf((acc[i][j][r] + bv) * scl);
            }
        }
    } else {
        __syncthreads();
        unsigned short* Lt = sm;              // 128 x 136
#pragma unroll
        for (int j = 0; j < 4; j++) {
            int cl = colBase + j * 16 + (l & 15);
            int o  = bn * 128 + cl - 2048;     // 0..1023 within V
            float bv = bias[bn * 128 + cl];
            float tr = trace[(o >> 6) * 4096 + (o & 63) * 65];
#pragma unroll
            for (int i = 0; i < 4; i++) {
                int s0 = rowBase + i * 16 + ((l >> 4) << 2);
                *(ushort4*)(Lt + cl * 136 + s0) =
                    pkbf4((acc[i][j][0] + bv) * tr, (acc[i][j][1] + bv) * tr,
                          (acc[i][j][2] + bv) * tr, (acc[i][j][3] + bv) * tr);
            }
        }
        __syncthreads();
#pragma unroll
        for (int p = 0; p < 8; ++p) {
            int dl  = (t >> 4) + p * 16;
            int sch = (t & 15) * 8;
            int o = bn * 128 + dl - 2048;
            int h = o >> 6, d = o & 63;
            s16x8 v = *(const s16x8*)(Lt + dl * 136 + sch);
            *(s16x8*)(Vt + (h * 64 + d) * S_LEN + bm * 128 + sch) = v;
        }
    }
}

// ---------------------------------------------------------------------------
// Kernel A (fallback, small ws): fp32-staged GEMM, same outputs
// ---------------------------------------------------------------------------
__global__ __launch_bounds__(256) void qkv_gemm_f32(
    const float* __restrict__ X, const float* __restrict__ W,
    const float* __restrict__ bias, const float* __restrict__ trace,
    unsigned short* __restrict__ Qb, unsigned short* __restrict__ Kb,
    unsigned short* __restrict__ Vt)
{
    __shared__ __align__(16) unsigned short sm[17408];
    unsigned short* As = sm;
    unsigned short* Bs = sm + 5120;

    const int t = threadIdx.x;
    const int l = t & 63;
    const int w = t >> 6;
    const int bm = blockIdx.y, bn = blockIdx.x;
    const int rowBase = (w >> 1) * 64;
    const int colBase = (w & 1) * 64;

    f32x4 acc[4][4];
#pragma unroll
    for (int i = 0; i < 4; i++)
#pragma unroll
        for (int j = 0; j < 4; j++) acc[i][j] = (f32x4)0.f;

    const int sr = t >> 3;
    const int sc = (t & 7) * 4;

    for (int kt = 0; kt < 32; ++kt) {
        const int k0 = kt * 32;
#pragma unroll
        for (int p = 0; p < 4; ++p) {
            int r = sr + p * 32;
            float4 xa = *(const float4*)(X + (bm * 128 + r) * 1024 + k0 + sc);
            float4 wb = *(const float4*)(W + (bn * 128 + r) * 1024 + k0 + sc);
            *(ushort4*)(As + r * 40 + sc) = pkbf4(xa.x, xa.y, xa.z, xa.w);
            *(ushort4*)(Bs + r * 40 + sc) = pkbf4(wb.x, wb.y, wb.z, wb.w);
        }
        __syncthreads();

        s16x8 af[4], bf[4];
#pragma unroll
        for (int i = 0; i < 4; i++) {
            af[i] = *(const s16x8*)(As + (rowBase + i * 16 + (l & 15)) * 40 + (l >> 4) * 8);
            bf[i] = *(const s16x8*)(Bs + (colBase + i * 16 + (l & 15)) * 40 + (l >> 4) * 8);
        }
#pragma unroll
        for (int i = 0; i < 4; i++)
#pragma unroll
            for (int j = 0; j < 4; j++)
                acc[i][j] = __builtin_amdgcn_mfma_f32_16x16x32_bf16(af[i], bf[j], acc[i][j], 0, 0, 0);
        __syncthreads();
    }

    if (bn < 16) {
#pragma unroll
        for (int j = 0; j < 4; j++) {
            int col = bn * 128 + colBase + j * 16 + (l & 15);
            float bv = bias[col];
            int region = col >> 10;
            int within = col & 1023;
            int h = within >> 6, d = within & 63;
            unsigned short* dst = (region == 0) ? Qb : Kb;
            float scl = (region == 0) ? CEXP : 1.0f;
#pragma unroll
            for (int i = 0; i < 4; i++) {
                int s0 = bm * 128 + rowBase + i * 16 + ((l >> 4) << 2);
#pragma unroll
                for (int r = 0; r < 4; r++)
                    dst[(h * S_LEN + s0 + r) * 64 + d] = f2bf((acc[i][j][r] + bv) * scl);
            }
        }
    } else {
        __syncthreads();
        unsigned short* Lt = sm;
#pragma unroll
        for (int j = 0; j < 4; j++) {
            int cl = colBase + j * 16 + (l & 15);
            int o  = bn * 128 + cl - 2048;
            float bv = bias[bn * 128 + cl];
            float tr = trace[(o >> 6) * 4096 + (o & 63) * 65];
#pragma unroll
            for (int i = 0; i < 4; i++) {
                int s0 = rowBase + i * 16 + ((l >> 4) << 2);
                *(ushort4*)(Lt + cl * 136 + s0) =
                    pkbf4((acc[i][j][0] + bv) * tr, (acc[i][j][1] + bv) * tr,
                          (acc[i][j][2] + bv) * tr, (acc[i][j][3] + bv) * tr);
            }
        }
        __syncthreads();
#pragma unroll
        for (int p = 0; p < 8; ++p) {
            int dl  = (t >> 4) + p * 16;
            int sch = (t & 15) * 8;
            int o = bn * 128 + dl - 2048;
            int h = o >> 6, d = o & 63;
            s16x8 v = *(const s16x8*)(Lt + dl * 136 + sch);
            *(s16x8*)(Vt + (h * 64 + d) * S_LEN + bm * 128 + sch) = v;
        }
    }
}

// ---------------------------------------------------------------------------
// Kernel B: flash attention. R2 changes (vs R0 95.6 µs baseline; R1's
// reg-staged dbuf spilled -> 261MB scratch writes, reverted):
//  1. K/V staging via global_load_lds DMA: ZERO staging registers (R1's
//     spill cause removed). LDS rows linear [64][64] shorts (DMA needs
//     contiguous dest, rule #21); bank conflicts on ds_read fixed by
//     T2 XOR swizzle chunk^=(row&7), applied BOTH on the pre-swizzled
//     global source addresses and on the read side (involution).
//  2. Double-buffered: DMA for tile kt+1 issued right after the barrier;
//     the barrier's implicit vmcnt(0) drain at top of kt+1 completes it.
//     One barrier per kt (was 2), no exposed global latency.
//  3. T12 (hardware-verified correct in R1): P built in-register via
//     cvt_pk + permlane32_swap; no P LDS round-trip. Hand-unrolled into
//     4 named blocks -> no f32x16 copies, no runtime indexing (rule #20).
//  4. T5 setprio(1) around both MFMA clusters.
// LDS: 4 staging bufs x 16KB = 64KB; sm sized 69632B for fp32 epilogue
// reuse; +1KB lArr -> 70656 B, 2 blocks/CU.
// ---------------------------------------------------------------------------
__global__ __launch_bounds__(512, 4) void attn(
    const unsigned short* __restrict__ Qb, const unsigned short* __restrict__ Kb,
    const unsigned short* __restrict__ Vt, float* __restrict__ out)
{
    __shared__ __align__(16) unsigned short sm[34816];   // 69632 B
    __shared__ float lArr[256];

    const int t = threadIdx.x;
    const int l = t & 63;
    const int w = t >> 6;            // 0..7
    const int g = w >> 2;            // kv half
    const int wg = w & 3;            // wave within group
    const int wq = w & 3;            // q sub-tile
    // XCD swizzle: xcd = bid%8 owns heads {2*xcd, 2*xcd+1}
    const int bid = blockIdx.x;
    const int xcd = bid & 7;
    const int j   = bid >> 3;        // 0..63
    const int h   = xcd * 2 + (j & 1);
    const int qblk = j >> 1;         // 0..31
    const int qbase = qblk * 128 + wq * 32;
    const int l31 = l & 31;
    const int lh  = l >> 5;
    const int swz = l31 & 7;         // read-side XOR (row&7)

    s16x8 qf[4];
#pragma unroll
    for (int ks = 0; ks < 4; ks++)
        qf[ks] = *(const s16x8*)(Qb + (h * S_LEN + qbase + l31) * 64 + ks * 16 + lh * 8);

    f32x16 O0 = (f32x16)0.f, O1 = (f32x16)0.f;
    float2 lpA; lpA.x = 0.f; lpA.y = 0.f;
    float2 lpB; lpB.x = 0.f; lpB.y = 0.f;

    // --- DMA staging addresses -------------------------------------------
    // Physical 16B chunk p = (wg*2+j)*64 + lane; row = p>>3, pc = p&7.
    // Logical chunk c = pc ^ (row&7)  (inverse-swizzled global source).
    // Wave instr j writes LDS linearly at base + (wg*2+j)*1024B + lane*16.
    const int p0 = (wg * 2 + 0) * 64 + l;
    const int p1 = (wg * 2 + 1) * 64 + l;
    const int r0_ = p0 >> 3, c0_ = (p0 & 7) ^ (r0_ & 7);
    const int r1_ = p1 >> 3, c1_ = (p1 & 7) ^ (r1_ & 7);
    const unsigned short* gk0 = Kb + (h * S_LEN + g * 2048 + r0_) * 64 + c0_ * 8;
    const unsigned short* gk1 = Kb + (h * S_LEN + g * 2048 + r1_) * 64 + c1_ * 8;
    const unsigned short* gv0 = Vt + (h * 64 + r0_) * S_LEN + g * 2048 + c0_ * 8;
    const unsigned short* gv1 = Vt + (h * 64 + r1_) * S_LEN + g * 2048 + c1_ * 8;

    // prologue: stage tile 0 into buf 0
    {
        unsigned short* kb_ = sm + g * 8192 + wg * 1024;
        async16(gk0, kb_);
        async16(gk1, kb_ + 512);
        async16(gv0, kb_ + 4096);
        async16(gv1, kb_ + 4096 + 512);
    }

    for (int kt = 0; kt < 32; ++kt) {
        __syncthreads();   // implicit vmcnt(0): buf[kt&1] DMA done everywhere;
                           // all waves finished reading buf[kt&1 ^ 1]
        const unsigned short* sb  = sm + ((kt & 1) * 2 + g) * 8192;
        const unsigned short* vbs = sb + 4096;

        // issue next tile's DMA into the other buffer (zero registers)
        if (kt < 31) {
            gk0 += 4096; gk1 += 4096; gv0 += 64; gv1 += 64;
            unsigned short* kb_ = sm + (((kt + 1) & 1) * 2 + g) * 8192 + wg * 1024;
            async16(gk0, kb_);
            async16(gk1, kb_ + 512);
            async16(gv0, kb_ + 4096);
            async16(gv1, kb_ + 4096 + 512);
        }

        // S^T[kv][q] = K x Q^T  (scores pre-scaled via Q); swizzled reads
        f32x16 S0 = (f32x16)0.f, S1 = (f32x16)0.f;
        __builtin_amdgcn_s_setprio(1);
#pragma unroll
        for (int ks = 0; ks < 4; ks++) {
            const int off = ((ks * 2 + lh) ^ swz) * 8;
            s16x8 a0 = *(const s16x8*)(sb + l31 * 64 + off);
            s16x8 a1 = *(const s16x8*)(sb + (32 + l31) * 64 + off);
            S0 = __builtin_amdgcn_mfma_f32_32x32x16_bf16(a0, qf[ks], S0, 0, 0, 0);
            S1 = __builtin_amdgcn_mfma_f32_32x32x16_bf16(a1, qf[ks], S1, 0, 0, 0);
        }
        __builtin_amdgcn_s_setprio(0);

#pragma unroll
        for (int i = 0; i < 16; i += 4) {
            float p0v = __builtin_amdgcn_exp2f(S0[i+0]); S0[i+0] = p0v; lpA.x += p0v;
            float p1v = __builtin_amdgcn_exp2f(S0[i+1]); S0[i+1] = p1v; lpA.y += p1v;
            float p2v = __builtin_amdgcn_exp2f(S0[i+2]); S0[i+2] = p2v; lpB.x += p2v;
            float p3v = __builtin_amdgcn_exp2f(S0[i+3]); S0[i+3] = p3v; lpB.y += p3v;
        }
#pragma unroll
        for (int i = 0; i < 16; i += 4) {
            float p0v = __builtin_amdgcn_exp2f(S1[i+0]); S1[i+0] = p0v; lpA.x += p0v;
            float p1v = __builtin_amdgcn_exp2f(S1[i+1]); S1[i+1] = p1v; lpA.y += p1v;
            float p2v = __builtin_amdgcn_exp2f(S1[i+2]); S1[i+2] = p2v; lpB.x += p2v;
            float p3v = __builtin_amdgcn_exp2f(S1[i+3]); S1[i+3] = p3v; lpB.y += p3v;
        }

        // T12: O^T[d][q] += V^T x P^T, P built in-register (R1-verified map).
        // Hand-unrolled; named S0/S1 only, constant indices throughout.
        __builtin_amdgcn_s_setprio(1);
#define PVBLK(SX, BO, KS) do {                                               \
        unsigned pa0 = pku(SX[(BO)+0], SX[(BO)+1]);                          \
        unsigned pc0 = pku(SX[(BO)+4], SX[(BO)+5]);                          \
        unsigned pa1 = pku(SX[(BO)+2], SX[(BO)+3]);                          \
        unsigned pc1 = pku(SX[(BO)+6], SX[(BO)+7]);                          \
        auto r0 = __builtin_amdgcn_permlane32_swap(pa0, pc0, false, false);  \
        auto r1 = __builtin_amdgcn_permlane32_swap(pa1, pc1, false, false);  \
        union { s16x8 v; unsigned u[4]; } pb_;                               \
        pb_.u[0] = r0[0]; pb_.u[1] = r1[0]; pb_.u[2] = r0[1]; pb_.u[3] = r1[1]; \
        const int offv = (((KS) * 2 + lh) ^ swz) * 8;                        \
        s16x8 av0 = *(const s16x8*)(vbs + l31 * 64 + offv);                  \
        s16x8 av1 = *(const s16x8*)(vbs + (32 + l31) * 64 + offv);           \
        O0 = __builtin_amdgcn_mfma_f32_32x32x16_bf16(av0, pb_.v, O0, 0, 0, 0); \
        O1 = __builtin_amdgcn_mfma_f32_32x32x16_bf16(av1, pb_.v, O1, 0, 0, 0); \
    } while (0)
        PVBLK(S0, 0, 0);
        PVBLK(S0, 8, 1);
        PVBLK(S1, 0, 2);
        PVBLK(S1, 8, 3);
#undef PVBLK
        __builtin_amdgcn_s_setprio(0);
    }

    // per-wave l partial for q = qbase + l31
    float l_part = (lpA.x + lpA.y) + (lpB.x + lpB.y);
    float l_tot = l_part + __shfl_xor(l_part, 32);
    if (lh == 0) lArr[w * 32 + l31] = l_tot;

    __syncthreads();    // drain last PV's LDS reads before Lo overwrites sm

    // stash raw O^T (fp32) per wave: Lo[w][q 0..31][d 0..67(pad)]
    float* Lo = (float*)sm + w * 2176;
#pragma unroll
    for (int dt = 0; dt < 2; ++dt) {
        const f32x16& Ox = dt ? O1 : O0;
#pragma unroll
        for (int gq = 0; gq < 4; ++gq) {
            int d0 = dt * 32 + gq * 8 + lh * 4;
            float4 vv;
            vv.x = Ox[gq*4+0]; vv.y = Ox[gq*4+1]; vv.z = Ox[gq*4+2]; vv.w = Ox[gq*4+3];
            *(float4*)(Lo + l31 * 68 + d0) = vv;
        }
    }
    __syncthreads();

    // waves 0-3: combine the two kv-half partials, normalize, store
    if (w < 4) {
        const float* LoA = (float*)sm + w * 2176;
        const float* LoB = (float*)sm + (w + 4) * 2176;
#pragma unroll
        for (int it = 0; it < 8; ++it) {
            int ql = it * 4 + (l >> 4);
            float invl = 1.0f / (lArr[w * 32 + ql] + lArr[(w + 4) * 32 + ql]);
            float4 a = *(const float4*)(LoA + ql * 68 + (l & 15) * 4);
            float4 b = *(const float4*)(LoB + ql * 68 + (l & 15) * 4);
            float4 vv;
            vv.x = (a.x + b.x) * invl;
            vv.y = (a.y + b.y) * invl;
            vv.z = (a.z + b.z) * invl;
            vv.w = (a.w + b.w) * invl;
            *(float4*)(out + (qblk * 128 + w * 32 + ql) * 1024 + h * 64 + (l & 15) * 4) = vv;
        }
    }
}

extern "C" void kernel_launch(void* const* d_in, const int* in_sizes, int n_in,
                              void* d_out, int out_size, void* d_ws, size_t ws_size,
                              hipStream_t stream) {
    const float* X     = (const float*)d_in[0];   // [1,4096,1024]
    const float* W     = (const float*)d_in[1];   // [3072,1024]
    const float* bias  = (const float*)d_in[2];   // [3072]
    const float* trace = (const float*)d_in[3];   // [16,64,64]
    float* out = (float*)d_out;

    unsigned short* Qb = (unsigned short*)d_ws;            // 8 MiB [h][s][d] (pre-scaled by CEXP)
    unsigned short* Kb = Qb + 4194304;                     // 8 MiB [h][s][d]
    unsigned short* Vt = Kb + 4194304;                     // 8 MiB [h][d][s] (pre-scaled by trace diag)
    unsigned short* Xb = Vt + 4194304;                     // 8 MiB bf16 X
    unsigned short* Wb = Xb + 4194304;                     // 6 MiB bf16 W

    const size_t NEED_BF16 = (size_t)3 * 8388608 + 8388608 + 6291456;

    if (ws_size >= NEED_BF16) {
        cvt_bf16<<<3584, 256, 0, stream>>>(X, W, Xb, Wb);
        qkv_gemm_bf16<<<dim3(24, 32), 256, 0, stream>>>(Xb, Wb, bias, trace, Qb, Kb, Vt);
    } else {
        qkv_gemm_f32<<<dim3(24, 32), 256, 0, stream>>>(X, W, bias, trace, Qb, Kb, Vt);
    }
    attn<<<512, 512, 0, stream>>>(Qb, Kb, Vt, out);
}

// Round 5
// 206.810 us; speedup vs baseline: 1.3751x; 1.0074x over previous
//
#include <hip/hip_runtime.h>
#include <hip/hip_bf16.h>
#include <stdint.h>

#define S_LEN 4096

typedef short s16x8  __attribute__((ext_vector_type(8)));
typedef float f32x4  __attribute__((ext_vector_type(4)));
typedef float f32x16 __attribute__((ext_vector_type(16)));

// log2(e)/8 : folded into Q at QKV epilogue; attn does exp2(score) directly
#define CEXP 0.18033688011112042f

__device__ __forceinline__ unsigned short f2bf(float f) {
    union { float f; unsigned u; } v; v.f = f;
    unsigned r = v.u + 0x7fffu + ((v.u >> 16) & 1u);
    return (unsigned short)(r >> 16);
}

__device__ __forceinline__ ushort2 pkbf(float a, float b) {
    float2 f; f.x = a; f.y = b;
    __hip_bfloat162 h = __float22bfloat162_rn(f);
    union { __hip_bfloat162 h; ushort2 u; } cv; cv.h = h;
    return cv.u;
}

__device__ __forceinline__ ushort4 pkbf4(float x, float y, float z, float w) {
    ushort2 lo = pkbf(x, y), hi = pkbf(z, w);
    ushort4 r; r.x = lo.x; r.y = lo.y; r.z = hi.x; r.w = hi.y;
    return r;
}

__device__ __forceinline__ unsigned pku(float a, float b) {
    union { ushort2 s; unsigned u; } c; c.s = pkbf(a, b); return c.u;
}

typedef const __attribute__((address_space(1))) void* gas_t;
typedef __attribute__((address_space(3))) void* sas_t;

__device__ __forceinline__ void async16(const void* g, void* s) {
    __builtin_amdgcn_global_load_lds((gas_t)g, (sas_t)s, 16, 0, 0);
}

// ---------------------------------------------------------------------------
// fp32 -> bf16 convert for X (4194304) and W (3145728). 8 elems/thread.
// ---------------------------------------------------------------------------
__global__ __launch_bounds__(256) void cvt_bf16(
    const float* __restrict__ X, const float* __restrict__ W,
    unsigned short* __restrict__ Xb, unsigned short* __restrict__ Wb)
{
    const long NX = 4194304;
    long i = (long)(blockIdx.x * 256 + threadIdx.x) * 8;
    const float* src; unsigned short* dst; long off;
    if (i < NX) { src = X; dst = Xb; off = i; }
    else        { src = W; dst = Wb; off = i - NX; }
    float4 a = *(const float4*)(src + off);
    float4 b = *(const float4*)(src + off + 4);
    union { s16x8 v; ushort4 q[2]; } o;
    o.q[0] = pkbf4(a.x, a.y, a.z, a.w);
    o.q[1] = pkbf4(b.x, b.y, b.z, b.w);
    *(s16x8*)(dst + off) = o.v;
}

// ---------------------------------------------------------------------------
// Kernel A (primary): qkv = Xb @ Wb^T + b, bf16 in, m97-style staging.
// R4b: K-loop REVERTED to the R2-proven 2-barrier single-buffer structure
// (R3's dbuf pipeline is the suspect for two consecutive container
// failures; it stays out until infra is proven healthy). KEPT from R3:
// the vectorized Q/K epilogue (acc -> LDS transpose [128][136] -> s16x8
// 16B/lane stores, replacing 64 scalar 2-byte stores/thread). Fits the
// original 34816 B LDS; hang-free by construction (uniform branch,
// uniform barriers, bounded addresses).
// ---------------------------------------------------------------------------
__global__ __launch_bounds__(256) void qkv_gemm_bf16(
    const unsigned short* __restrict__ Xb, const unsigned short* __restrict__ Wb,
    const float* __restrict__ bias, const float* __restrict__ trace,
    unsigned short* __restrict__ Qb, unsigned short* __restrict__ Kb,
    unsigned short* __restrict__ Vt)
{
    __shared__ __align__(16) unsigned short sm[17408];   // 34816 B
    unsigned short* As = sm;            // [128][64] bf16, unpadded (async dst)
    unsigned short* Bs = sm + 8192;     // [128][64]

    const int t = threadIdx.x;
    const int l = t & 63;
    const int w = t >> 6;
    const int bm = blockIdx.y, bn = blockIdx.x;
    const int rowBase = (w >> 1) * 64;
    const int colBase = (w & 1) * 64;

    f32x4 acc[4][4];
#pragma unroll
    for (int i = 0; i < 4; i++)
#pragma unroll
        for (int j = 0; j < 4; j++) acc[i][j] = (f32x4)0.f;

    const int srow = l >> 3;        // 0..7
    const int scol = (l & 7) * 8;   // shorts

    for (int kt = 0; kt < 16; ++kt) {
        const int k0 = kt * 64;
#pragma unroll
        for (int c = 0; c < 4; ++c) {
            int m = w * 4 + c;                    // chunk 0..15 (8 rows each)
            const unsigned short* ga = Xb + (bm * 128 + m * 8 + srow) * 1024 + k0 + scol;
            const unsigned short* gb = Wb + (bn * 128 + m * 8 + srow) * 1024 + k0 + scol;
            async16(ga, As + m * 512);
            async16(gb, Bs + m * 512);
        }
        __syncthreads();

#pragma unroll
        for (int kc = 0; kc < 2; ++kc) {
            s16x8 af[4], bf[4];
#pragma unroll
            for (int i = 0; i < 4; i++) {
                af[i] = *(const s16x8*)(As + (rowBase + i * 16 + (l & 15)) * 64 + kc * 32 + (l >> 4) * 8);
                bf[i] = *(const s16x8*)(Bs + (colBase + i * 16 + (l & 15)) * 64 + kc * 32 + (l >> 4) * 8);
            }
#pragma unroll
            for (int i = 0; i < 4; i++)
#pragma unroll
                for (int j = 0; j < 4; j++)
                    acc[i][j] = __builtin_amdgcn_mfma_f32_16x16x32_bf16(af[i], bf[j], acc[i][j], 0, 0, 0);
        }
        __syncthreads();
    }

    if (bn < 16) {
        // Q/K epilogue: LDS transpose -> vectorized 16B stores (kept from R3).
        unsigned short* Ls = sm;                  // [128 s][136 c]
        const int region = bn >> 3;               // 0 = Q (bn<8), 1 = K
        unsigned short* dst = region ? Kb : Qb;
        const float scl = region ? 1.0f : CEXP;
#pragma unroll
        for (int j = 0; j < 4; j++) {
            int cl = colBase + j * 16 + (l & 15);          // block-local col
            float bv = bias[bn * 128 + cl];
#pragma unroll
            for (int i = 0; i < 4; i++) {
                int s0 = rowBase + i * 16 + ((l >> 4) << 2);
#pragma unroll
                for (int r = 0; r < 4; r++)
                    Ls[(s0 + r) * 136 + cl] = f2bf((acc[i][j][r] + bv) * scl);
            }
        }
        __syncthreads();
#pragma unroll
        for (int p = 0; p < 8; ++p) {
            int tk = p * 256 + t;
            int s  = tk >> 4;                  // 0..127
            int ch = tk & 15;                  // 0..15 (8-col chunk)
            int gc = bn * 128 + ch * 8;
            int h  = (gc >> 6) & 15, d = gc & 63;
            s16x8 v = *(const s16x8*)(Ls + s * 136 + ch * 8);
            *(s16x8*)(dst + (h * S_LEN + bm * 128 + s) * 64 + d) = v;
        }
    } else {
        __syncthreads();
        unsigned short* Lt = sm;              // 128 x 136
#pragma unroll
        for (int j = 0; j < 4; j++) {
            int cl = colBase + j * 16 + (l & 15);
            int o  = bn * 128 + cl - 2048;     // 0..1023 within V
            float bv = bias[bn * 128 + cl];
            float tr = trace[(o >> 6) * 4096 + (o & 63) * 65];
#pragma unroll
            for (int i = 0; i < 4; i++) {
                int s0 = rowBase + i * 16 + ((l >> 4) << 2);
                *(ushort4*)(Lt + cl * 136 + s0) =
                    pkbf4((acc[i][j][0] + bv) * tr, (acc[i][j][1] + bv) * tr,
                          (acc[i][j][2] + bv) * tr, (acc[i][j][3] + bv) * tr);
            }
        }
        __syncthreads();
#pragma unroll
        for (int p = 0; p < 8; ++p) {
            int dl  = (t >> 4) + p * 16;
            int sch = (t & 15) * 8;
            int o = bn * 128 + dl - 2048;
            int h = o >> 6, d = o & 63;
            s16x8 v = *(const s16x8*)(Lt + dl * 136 + sch);
            *(s16x8*)(Vt + (h * 64 + d) * S_LEN + bm * 128 + sch) = v;
        }
    }
}

// ---------------------------------------------------------------------------
// Kernel A (fallback, small ws): fp32-staged GEMM, same outputs (unchanged)
// ---------------------------------------------------------------------------
__global__ __launch_bounds__(256) void qkv_gemm_f32(
    const float* __restrict__ X, const float* __restrict__ W,
    const float* __restrict__ bias, const float* __restrict__ trace,
    unsigned short* __restrict__ Qb, unsigned short* __restrict__ Kb,
    unsigned short* __restrict__ Vt)
{
    __shared__ __align__(16) unsigned short sm[17408];
    unsigned short* As = sm;
    unsigned short* Bs = sm + 5120;

    const int t = threadIdx.x;
    const int l = t & 63;
    const int w = t >> 6;
    const int bm = blockIdx.y, bn = blockIdx.x;
    const int rowBase = (w >> 1) * 64;
    const int colBase = (w & 1) * 64;

    f32x4 acc[4][4];
#pragma unroll
    for (int i = 0; i < 4; i++)
#pragma unroll
        for (int j = 0; j < 4; j++) acc[i][j] = (f32x4)0.f;

    const int sr = t >> 3;
    const int sc = (t & 7) * 4;

    for (int kt = 0; kt < 32; ++kt) {
        const int k0 = kt * 32;
#pragma unroll
        for (int p = 0; p < 4; ++p) {
            int r = sr + p * 32;
            float4 xa = *(const float4*)(X + (bm * 128 + r) * 1024 + k0 + sc);
            float4 wb = *(const float4*)(W + (bn * 128 + r) * 1024 + k0 + sc);
            *(ushort4*)(As + r * 40 + sc) = pkbf4(xa.x, xa.y, xa.z, xa.w);
            *(ushort4*)(Bs + r * 40 + sc) = pkbf4(wb.x, wb.y, wb.z, wb.w);
        }
        __syncthreads();

        s16x8 af[4], bf[4];
#pragma unroll
        for (int i = 0; i < 4; i++) {
            af[i] = *(const s16x8*)(As + (rowBase + i * 16 + (l & 15)) * 40 + (l >> 4) * 8);
            bf[i] = *(const s16x8*)(Bs + (colBase + i * 16 + (l & 15)) * 40 + (l >> 4) * 8);
        }
#pragma unroll
        for (int i = 0; i < 4; i++)
#pragma unroll
            for (int j = 0; j < 4; j++)
                acc[i][j] = __builtin_amdgcn_mfma_f32_16x16x32_bf16(af[i], bf[j], acc[i][j], 0, 0, 0);
        __syncthreads();
    }

    if (bn < 16) {
#pragma unroll
        for (int j = 0; j < 4; j++) {
            int col = bn * 128 + colBase + j * 16 + (l & 15);
            float bv = bias[col];
            int region = col >> 10;
            int within = col & 1023;
            int h = within >> 6, d = within & 63;
            unsigned short* dst = (region == 0) ? Qb : Kb;
            float scl = (region == 0) ? CEXP : 1.0f;
#pragma unroll
            for (int i = 0; i < 4; i++) {
                int s0 = bm * 128 + rowBase + i * 16 + ((l >> 4) << 2);
#pragma unroll
                for (int r = 0; r < 4; r++)
                    dst[(h * S_LEN + s0 + r) * 64 + d] = f2bf((acc[i][j][r] + bv) * scl);
            }
        }
    } else {
        __syncthreads();
        unsigned short* Lt = sm;
#pragma unroll
        for (int j = 0; j < 4; j++) {
            int cl = colBase + j * 16 + (l & 15);
            int o  = bn * 128 + cl - 2048;
            float bv = bias[bn * 128 + cl];
            float tr = trace[(o >> 6) * 4096 + (o & 63) * 65];
#pragma unroll
            for (int i = 0; i < 4; i++) {
                int s0 = rowBase + i * 16 + ((l >> 4) << 2);
                *(ushort4*)(Lt + cl * 136 + s0) =
                    pkbf4((acc[i][j][0] + bv) * tr, (acc[i][j][1] + bv) * tr,
                          (acc[i][j][2] + bv) * tr, (acc[i][j][3] + bv) * tr);
            }
        }
        __syncthreads();
#pragma unroll
        for (int p = 0; p < 8; ++p) {
            int dl  = (t >> 4) + p * 16;
            int sch = (t & 15) * 8;
            int o = bn * 128 + dl - 2048;
            int h = o >> 6, d = o & 63;
            s16x8 v = *(const s16x8*)(Lt + dl * 136 + sch);
            *(s16x8*)(Vt + (h * 64 + d) * S_LEN + bm * 128 + sch) = v;
        }
    }
}

// ---------------------------------------------------------------------------
// Kernel B: flash attention (UNCHANGED from R2 89.4 µs version).
// DMA dbuf staging (zero staging regs), 1 barrier/kt, T12 in-register P,
// T5 setprio. LDS: 4 staging bufs x 16KB + epilogue reuse = 69632 B.
// ---------------------------------------------------------------------------
__global__ __launch_bounds__(512, 4) void attn(
    const unsigned short* __restrict__ Qb, const unsigned short* __restrict__ Kb,
    const unsigned short* __restrict__ Vt, float* __restrict__ out)
{
    __shared__ __align__(16) unsigned short sm[34816];   // 69632 B
    __shared__ float lArr[256];

    const int t = threadIdx.x;
    const int l = t & 63;
    const int w = t >> 6;            // 0..7
    const int g = w >> 2;            // kv half
    const int wg = w & 3;            // wave within group
    const int wq = w & 3;            // q sub-tile
    // XCD swizzle: xcd = bid%8 owns heads {2*xcd, 2*xcd+1}
    const int bid = blockIdx.x;
    const int xcd = bid & 7;
    const int j   = bid >> 3;        // 0..63
    const int h   = xcd * 2 + (j & 1);
    const int qblk = j >> 1;         // 0..31
    const int qbase = qblk * 128 + wq * 32;
    const int l31 = l & 31;
    const int lh  = l >> 5;
    const int swz = l31 & 7;         // read-side XOR (row&7)

    s16x8 qf[4];
#pragma unroll
    for (int ks = 0; ks < 4; ks++)
        qf[ks] = *(const s16x8*)(Qb + (h * S_LEN + qbase + l31) * 64 + ks * 16 + lh * 8);

    f32x16 O0 = (f32x16)0.f, O1 = (f32x16)0.f;
    float2 lpA; lpA.x = 0.f; lpA.y = 0.f;
    float2 lpB; lpB.x = 0.f; lpB.y = 0.f;

    // --- DMA staging addresses -------------------------------------------
    // Physical 16B chunk p = (wg*2+j)*64 + lane; row = p>>3, pc = p&7.
    // Logical chunk c = pc ^ (row&7)  (inverse-swizzled global source).
    // Wave instr j writes LDS linearly at base + (wg*2+j)*1024B + lane*16.
    const int p0 = (wg * 2 + 0) * 64 + l;
    const int p1 = (wg * 2 + 1) * 64 + l;
    const int r0_ = p0 >> 3, c0_ = (p0 & 7) ^ (r0_ & 7);
    const int r1_ = p1 >> 3, c1_ = (p1 & 7) ^ (r1_ & 7);
    const unsigned short* gk0 = Kb + (h * S_LEN + g * 2048 + r0_) * 64 + c0_ * 8;
    const unsigned short* gk1 = Kb + (h * S_LEN + g * 2048 + r1_) * 64 + c1_ * 8;
    const unsigned short* gv0 = Vt + (h * 64 + r0_) * S_LEN + g * 2048 + c0_ * 8;
    const unsigned short* gv1 = Vt + (h * 64 + r1_) * S_LEN + g * 2048 + c1_ * 8;

    // prologue: stage tile 0 into buf 0
    {
        unsigned short* kb_ = sm + g * 8192 + wg * 1024;
        async16(gk0, kb_);
        async16(gk1, kb_ + 512);
        async16(gv0, kb_ + 4096);
        async16(gv1, kb_ + 4096 + 512);
    }

    for (int kt = 0; kt < 32; ++kt) {
        __syncthreads();   // implicit vmcnt(0): buf[kt&1] DMA done everywhere;
                           // all waves finished reading buf[kt&1 ^ 1]
        const unsigned short* sb  = sm + ((kt & 1) * 2 + g) * 8192;
        const unsigned short* vbs = sb + 4096;

        // issue next tile's DMA into the other buffer (zero registers)
        if (kt < 31) {
            gk0 += 4096; gk1 += 4096; gv0 += 64; gv1 += 64;
            unsigned short* kb_ = sm + (((kt + 1) & 1) * 2 + g) * 8192 + wg * 1024;
            async16(gk0, kb_);
            async16(gk1, kb_ + 512);
            async16(gv0, kb_ + 4096);
            async16(gv1, kb_ + 4096 + 512);
        }

        // S^T[kv][q] = K x Q^T  (scores pre-scaled via Q); swizzled reads
        f32x16 S0 = (f32x16)0.f, S1 = (f32x16)0.f;
        __builtin_amdgcn_s_setprio(1);
#pragma unroll
        for (int ks = 0; ks < 4; ks++) {
            const int off = ((ks * 2 + lh) ^ swz) * 8;
            s16x8 a0 = *(const s16x8*)(sb + l31 * 64 + off);
            s16x8 a1 = *(const s16x8*)(sb + (32 + l31) * 64 + off);
            S0 = __builtin_amdgcn_mfma_f32_32x32x16_bf16(a0, qf[ks], S0, 0, 0, 0);
            S1 = __builtin_amdgcn_mfma_f32_32x32x16_bf16(a1, qf[ks], S1, 0, 0, 0);
        }
        __builtin_amdgcn_s_setprio(0);

#pragma unroll
        for (int i = 0; i < 16; i += 4) {
            float p0v = __builtin_amdgcn_exp2f(S0[i+0]); S0[i+0] = p0v; lpA.x += p0v;
            float p1v = __builtin_amdgcn_exp2f(S0[i+1]); S0[i+1] = p1v; lpA.y += p1v;
            float p2v = __builtin_amdgcn_exp2f(S0[i+2]); S0[i+2] = p2v; lpB.x += p2v;
            float p3v = __builtin_amdgcn_exp2f(S0[i+3]); S0[i+3] = p3v; lpB.y += p3v;
        }
#pragma unroll
        for (int i = 0; i < 16; i += 4) {
            float p0v = __builtin_amdgcn_exp2f(S1[i+0]); S1[i+0] = p0v; lpA.x += p0v;
            float p1v = __builtin_amdgcn_exp2f(S1[i+1]); S1[i+1] = p1v; lpA.y += p1v;
            float p2v = __builtin_amdgcn_exp2f(S1[i+2]); S1[i+2] = p2v; lpB.x += p2v;
            float p3v = __builtin_amdgcn_exp2f(S1[i+3]); S1[i+3] = p3v; lpB.y += p3v;
        }

        // T12: O^T[d][q] += V^T x P^T, P built in-register (R1-verified map).
        __builtin_amdgcn_s_setprio(1);
#define PVBLK(SX, BO, KS) do {                                               \
        unsigned pa0 = pku(SX[(BO)+0], SX[(BO)+1]);                          \
        unsigned pc0 = pku(SX[(BO)+4], SX[(BO)+5]);                          \
        unsigned pa1 = pku(SX[(BO)+2], SX[(BO)+3]);                          \
        unsigned pc1 = pku(SX[(BO)+6], SX[(BO)+7]);                          \
        auto r0 = __builtin_amdgcn_permlane32_swap(pa0, pc0, false, false);  \
        auto r1 = __builtin_amdgcn_permlane32_swap(pa1, pc1, false, false);  \
        union { s16x8 v; unsigned u[4]; } pb_;                               \
        pb_.u[0] = r0[0]; pb_.u[1] = r1[0]; pb_.u[2] = r0[1]; pb_.u[3] = r1[1]; \
        const int offv = (((KS) * 2 + lh) ^ swz) * 8;                        \
        s16x8 av0 = *(const s16x8*)(vbs + l31 * 64 + offv);                  \
        s16x8 av1 = *(const s16x8*)(vbs + (32 + l31) * 64 + offv);           \
        O0 = __builtin_amdgcn_mfma_f32_32x32x16_bf16(av0, pb_.v, O0, 0, 0, 0); \
        O1 = __builtin_amdgcn_mfma_f32_32x32x16_bf16(av1, pb_.v, O1, 0, 0, 0); \
    } while (0)
        PVBLK(S0, 0, 0);
        PVBLK(S0, 8, 1);
        PVBLK(S1, 0, 2);
        PVBLK(S1, 8, 3);
#undef PVBLK
        __builtin_amdgcn_s_setprio(0);
    }

    // per-wave l partial for q = qbase + l31
    float l_part = (lpA.x + lpA.y) + (lpB.x + lpB.y);
    float l_tot = l_part + __shfl_xor(l_part, 32);
    if (lh == 0) lArr[w * 32 + l31] = l_tot;

    __syncthreads();    // drain last PV's LDS reads before Lo overwrites sm

    // stash raw O^T (fp32) per wave: Lo[w][q 0..31][d 0..67(pad)]
    float* Lo = (float*)sm + w * 2176;
#pragma unroll
    for (int dt = 0; dt < 2; ++dt) {
        const f32x16& Ox = dt ? O1 : O0;
#pragma unroll
        for (int gq = 0; gq < 4; ++gq) {
            int d0 = dt * 32 + gq * 8 + lh * 4;
            float4 vv;
            vv.x = Ox[gq*4+0]; vv.y = Ox[gq*4+1]; vv.z = Ox[gq*4+2]; vv.w = Ox[gq*4+3];
            *(float4*)(Lo + l31 * 68 + d0) = vv;
        }
    }
    __syncthreads();

    // waves 0-3: combine the two kv-half partials, normalize, store
    if (w < 4) {
        const float* LoA = (float*)sm + w * 2176;
        const float* LoB = (float*)sm + (w + 4) * 2176;
#pragma unroll
        for (int it = 0; it < 8; ++it) {
            int ql = it * 4 + (l >> 4);
            float invl = 1.0f / (lArr[w * 32 + ql] + lArr[(w + 4) * 32 + ql]);
            float4 a = *(const float4*)(LoA + ql * 68 + (l & 15) * 4);
            float4 b = *(const float4*)(LoB + ql * 68 + (l & 15) * 4);
            float4 vv;
            vv.x = (a.x + b.x) * invl;
            vv.y = (a.y + b.y) * invl;
            vv.z = (a.z + b.z) * invl;
            vv.w = (a.w + b.w) * invl;
            *(float4*)(out + (qblk * 128 + w * 32 + ql) * 1024 + h * 64 + (l & 15) * 4) = vv;
        }
    }
}

extern "C" void kernel_launch(void* const* d_in, const int* in_sizes, int n_in,
                              void* d_out, int out_size, void* d_ws, size_t ws_size,
                              hipStream_t stream) {
    const float* X     = (const float*)d_in[0];   // [1,4096,1024]
    const float* W     = (const float*)d_in[1];   // [3072,1024]
    const float* bias  = (const float*)d_in[2];   // [3072]
    const float* trace = (const float*)d_in[3];   // [16,64,64]
    float* out = (float*)d_out;

    unsigned short* Qb = (unsigned short*)d_ws;            // 8 MiB [h][s][d] (pre-scaled by CEXP)
    unsigned short* Kb = Qb + 4194304;                     // 8 MiB [h][s][d]
    unsigned short* Vt = Kb + 4194304;                     // 8 MiB [h][d][s] (pre-scaled by trace diag)
    unsigned short* Xb = Vt + 4194304;                     // 8 MiB bf16 X
    unsigned short* Wb = Xb + 4194304;                     // 6 MiB bf16 W

    const size_t NEED_BF16 = (size_t)3 * 8388608 + 8388608 + 6291456;

    if (ws_size >= NEED_BF16) {
        cvt_bf16<<<3584, 256, 0, stream>>>(X, W, Xb, Wb);
        qkv_gemm_bf16<<<dim3(24, 32), 256, 0, stream>>>(Xb, Wb, bias, trace, Qb, Kb, Vt);
    } else {
        qkv_gemm_f32<<<dim3(24, 32), 256, 0, stream>>>(X, W, bias, trace, Qb, Kb, Vt);
    }
    attn<<<512, 512, 0, stream>>>(Qb, Kb, Vt, out);
}

// Round 6
// 200.693 us; speedup vs baseline: 1.4170x; 1.0305x over previous
//
#include <hip/hip_runtime.h>
#include <hip/hip_bf16.h>
#include <stdint.h>

#define S_LEN 4096

typedef short s16x8  __attribute__((ext_vector_type(8)));
typedef float f32x4  __attribute__((ext_vector_type(4)));
typedef float f32x16 __attribute__((ext_vector_type(16)));

// log2(e)/8 : folded into Q at QKV epilogue; attn does exp2(score) directly
#define CEXP 0.18033688011112042f

__device__ __forceinline__ unsigned short f2bf(float f) {
    union { float f; unsigned u; } v; v.f = f;
    unsigned r = v.u + 0x7fffu + ((v.u >> 16) & 1u);
    return (unsigned short)(r >> 16);
}

__device__ __forceinline__ ushort2 pkbf(float a, float b) {
    float2 f; f.x = a; f.y = b;
    __hip_bfloat162 h = __float22bfloat162_rn(f);
    union { __hip_bfloat162 h; ushort2 u; } cv; cv.h = h;
    return cv.u;
}

__device__ __forceinline__ ushort4 pkbf4(float x, float y, float z, float w) {
    ushort2 lo = pkbf(x, y), hi = pkbf(z, w);
    ushort4 r; r.x = lo.x; r.y = lo.y; r.z = hi.x; r.w = hi.y;
    return r;
}

__device__ __forceinline__ unsigned pku(float a, float b) {
    union { ushort2 s; unsigned u; } c; c.s = pkbf(a, b); return c.u;
}

typedef const __attribute__((address_space(1))) void* gas_t;
typedef __attribute__((address_space(3))) void* sas_t;

__device__ __forceinline__ void async16(const void* g, void* s) {
    __builtin_amdgcn_global_load_lds((gas_t)g, (sas_t)s, 16, 0, 0);
}

// ---------------------------------------------------------------------------
// fp32 -> bf16 convert for X (4194304) and W (3145728). 8 elems/thread.
// ---------------------------------------------------------------------------
__global__ __launch_bounds__(256) void cvt_bf16(
    const float* __restrict__ X, const float* __restrict__ W,
    unsigned short* __restrict__ Xb, unsigned short* __restrict__ Wb)
{
    const long NX = 4194304;
    long i = (long)(blockIdx.x * 256 + threadIdx.x) * 8;
    const float* src; unsigned short* dst; long off;
    if (i < NX) { src = X; dst = Xb; off = i; }
    else        { src = W; dst = Wb; off = i - NX; }
    float4 a = *(const float4*)(src + off);
    float4 b = *(const float4*)(src + off + 4);
    union { s16x8 v; ushort4 q[2]; } o;
    o.q[0] = pkbf4(a.x, a.y, a.z, a.w);
    o.q[1] = pkbf4(b.x, b.y, b.z, b.w);
    *(s16x8*)(dst + off) = o.v;
}

// ---------------------------------------------------------------------------
// Kernel A (primary): qkv = Xb @ Wb^T + b, bf16 in.
// R6: dbuf K-loop re-landed now that infra is proven healthy (R5 control
// passed; R3/R4 failures were acquisition-side: acquire_s 92s, push 686s).
//  1. Double-buffered As/Bs (64KB LDS), ONE barrier per kt:
//     {barrier (drains DMA for buf[kt&1]) -> issue DMA kt+1 into buf^1 ->
//      compute buf}. Removes the exposed DMA drain the 2-barrier
//     single-buffer loop paid on each of only 16 K-steps.
//  2. Vectorized Q/K epilogue (R5-verified): acc -> LDS transpose
//     [128][136] -> s16x8 16B/lane stores.
// V epilogue unchanged. dim3(24,32) grid unchanged (XCD-consistent).
// ---------------------------------------------------------------------------
__global__ __launch_bounds__(256) void qkv_gemm_bf16(
    const unsigned short* __restrict__ Xb, const unsigned short* __restrict__ Wb,
    const float* __restrict__ bias, const float* __restrict__ trace,
    unsigned short* __restrict__ Qb, unsigned short* __restrict__ Kb,
    unsigned short* __restrict__ Vt)
{
    __shared__ __align__(16) unsigned short sm[32768];   // 65536 B: 2 x (A 8192 + B 8192)

    const int t = threadIdx.x;
    const int l = t & 63;
    const int w = t >> 6;
    const int bm = blockIdx.y, bn = blockIdx.x;
    const int rowBase = (w >> 1) * 64;
    const int colBase = (w & 1) * 64;

    f32x4 acc[4][4];
#pragma unroll
    for (int i = 0; i < 4; i++)
#pragma unroll
        for (int j = 0; j < 4; j++) acc[i][j] = (f32x4)0.f;

    const int srow = l >> 3;        // 0..7
    const int scol = (l & 7) * 8;   // shorts

    // prologue: stage K-tile 0 into buf 0
    {
#pragma unroll
        for (int c = 0; c < 4; ++c) {
            int m = w * 4 + c;
            const unsigned short* ga = Xb + (bm * 128 + m * 8 + srow) * 1024 + scol;
            const unsigned short* gb = Wb + (bn * 128 + m * 8 + srow) * 1024 + scol;
            async16(ga, sm + m * 512);
            async16(gb, sm + 8192 + m * 512);
        }
    }

    for (int kt = 0; kt < 16; ++kt) {
        __syncthreads();   // implicit vmcnt(0): buf[kt&1] DMA complete everywhere;
                           // all waves done reading buf[kt&1 ^ 1]
        const unsigned short* As = sm + (kt & 1) * 16384;
        const unsigned short* Bs = As + 8192;

        if (kt < 15) {
            const int k0 = (kt + 1) * 64;
            unsigned short* An = sm + ((kt + 1) & 1) * 16384;
#pragma unroll
            for (int c = 0; c < 4; ++c) {
                int m = w * 4 + c;
                const unsigned short* ga = Xb + (bm * 128 + m * 8 + srow) * 1024 + k0 + scol;
                const unsigned short* gb = Wb + (bn * 128 + m * 8 + srow) * 1024 + k0 + scol;
                async16(ga, An + m * 512);
                async16(gb, An + 8192 + m * 512);
            }
        }

#pragma unroll
        for (int kc = 0; kc < 2; ++kc) {
            s16x8 af[4], bf[4];
#pragma unroll
            for (int i = 0; i < 4; i++) {
                af[i] = *(const s16x8*)(As + (rowBase + i * 16 + (l & 15)) * 64 + kc * 32 + (l >> 4) * 8);
                bf[i] = *(const s16x8*)(Bs + (colBase + i * 16 + (l & 15)) * 64 + kc * 32 + (l >> 4) * 8);
            }
#pragma unroll
            for (int i = 0; i < 4; i++)
#pragma unroll
                for (int j = 0; j < 4; j++)
                    acc[i][j] = __builtin_amdgcn_mfma_f32_16x16x32_bf16(af[i], bf[j], acc[i][j], 0, 0, 0);
        }
    }

    __syncthreads();   // all compute reads done; sm free for epilogue reuse

    if (bn < 16) {
        // Q/K epilogue: LDS transpose -> vectorized 16B stores.
        unsigned short* Ls = sm;                  // [128 s][136 c]
        const int region = bn >> 3;               // 0 = Q (bn<8), 1 = K
        unsigned short* dst = region ? Kb : Qb;
        const float scl = region ? 1.0f : CEXP;
#pragma unroll
        for (int j = 0; j < 4; j++) {
            int cl = colBase + j * 16 + (l & 15);          // block-local col
            float bv = bias[bn * 128 + cl];
#pragma unroll
            for (int i = 0; i < 4; i++) {
                int s0 = rowBase + i * 16 + ((l >> 4) << 2);
#pragma unroll
                for (int r = 0; r < 4; r++)
                    Ls[(s0 + r) * 136 + cl] = f2bf((acc[i][j][r] + bv) * scl);
            }
        }
        __syncthreads();
#pragma unroll
        for (int p = 0; p < 8; ++p) {
            int tk = p * 256 + t;
            int s  = tk >> 4;                  // 0..127
            int ch = tk & 15;                  // 0..15 (8-col chunk)
            int gc = bn * 128 + ch * 8;
            int h  = (gc >> 6) & 15, d = gc & 63;
            s16x8 v = *(const s16x8*)(Ls + s * 136 + ch * 8);
            *(s16x8*)(dst + (h * S_LEN + bm * 128 + s) * 64 + d) = v;
        }
    } else {
        unsigned short* Lt = sm;              // 128 x 136
#pragma unroll
        for (int j = 0; j < 4; j++) {
            int cl = colBase + j * 16 + (l & 15);
            int o  = bn * 128 + cl - 2048;     // 0..1023 within V
            float bv = bias[bn * 128 + cl];
            float tr = trace[(o >> 6) * 4096 + (o & 63) * 65];
#pragma unroll
            for (int i = 0; i < 4; i++) {
                int s0 = rowBase + i * 16 + ((l >> 4) << 2);
                *(ushort4*)(Lt + cl * 136 + s0) =
                    pkbf4((acc[i][j][0] + bv) * tr, (acc[i][j][1] + bv) * tr,
                          (acc[i][j][2] + bv) * tr, (acc[i][j][3] + bv) * tr);
            }
        }
        __syncthreads();
#pragma unroll
        for (int p = 0; p < 8; ++p) {
            int dl  = (t >> 4) + p * 16;
            int sch = (t & 15) * 8;
            int o = bn * 128 + dl - 2048;
            int h = o >> 6, d = o & 63;
            s16x8 v = *(const s16x8*)(Lt + dl * 136 + sch);
            *(s16x8*)(Vt + (h * 64 + d) * S_LEN + bm * 128 + sch) = v;
        }
    }
}

// ---------------------------------------------------------------------------
// Kernel A (fallback, small ws): fp32-staged GEMM, same outputs (unchanged)
// ---------------------------------------------------------------------------
__global__ __launch_bounds__(256) void qkv_gemm_f32(
    const float* __restrict__ X, const float* __restrict__ W,
    const float* __restrict__ bias, const float* __restrict__ trace,
    unsigned short* __restrict__ Qb, unsigned short* __restrict__ Kb,
    unsigned short* __restrict__ Vt)
{
    __shared__ __align__(16) unsigned short sm[17408];
    unsigned short* As = sm;
    unsigned short* Bs = sm + 5120;

    const int t = threadIdx.x;
    const int l = t & 63;
    const int w = t >> 6;
    const int bm = blockIdx.y, bn = blockIdx.x;
    const int rowBase = (w >> 1) * 64;
    const int colBase = (w & 1) * 64;

    f32x4 acc[4][4];
#pragma unroll
    for (int i = 0; i < 4; i++)
#pragma unroll
        for (int j = 0; j < 4; j++) acc[i][j] = (f32x4)0.f;

    const int sr = t >> 3;
    const int sc = (t & 7) * 4;

    for (int kt = 0; kt < 32; ++kt) {
        const int k0 = kt * 32;
#pragma unroll
        for (int p = 0; p < 4; ++p) {
            int r = sr + p * 32;
            float4 xa = *(const float4*)(X + (bm * 128 + r) * 1024 + k0 + sc);
            float4 wb = *(const float4*)(W + (bn * 128 + r) * 1024 + k0 + sc);
            *(ushort4*)(As + r * 40 + sc) = pkbf4(xa.x, xa.y, xa.z, xa.w);
            *(ushort4*)(Bs + r * 40 + sc) = pkbf4(wb.x, wb.y, wb.z, wb.w);
        }
        __syncthreads();

        s16x8 af[4], bf[4];
#pragma unroll
        for (int i = 0; i < 4; i++) {
            af[i] = *(const s16x8*)(As + (rowBase + i * 16 + (l & 15)) * 40 + (l >> 4) * 8);
            bf[i] = *(const s16x8*)(Bs + (colBase + i * 16 + (l & 15)) * 40 + (l >> 4) * 8);
        }
#pragma unroll
        for (int i = 0; i < 4; i++)
#pragma unroll
            for (int j = 0; j < 4; j++)
                acc[i][j] = __builtin_amdgcn_mfma_f32_16x16x32_bf16(af[i], bf[j], acc[i][j], 0, 0, 0);
        __syncthreads();
    }

    if (bn < 16) {
#pragma unroll
        for (int j = 0; j < 4; j++) {
            int col = bn * 128 + colBase + j * 16 + (l & 15);
            float bv = bias[col];
            int region = col >> 10;
            int within = col & 1023;
            int h = within >> 6, d = within & 63;
            unsigned short* dst = (region == 0) ? Qb : Kb;
            float scl = (region == 0) ? CEXP : 1.0f;
#pragma unroll
            for (int i = 0; i < 4; i++) {
                int s0 = bm * 128 + rowBase + i * 16 + ((l >> 4) << 2);
#pragma unroll
                for (int r = 0; r < 4; r++)
                    dst[(h * S_LEN + s0 + r) * 64 + d] = f2bf((acc[i][j][r] + bv) * scl);
            }
        }
    } else {
        __syncthreads();
        unsigned short* Lt = sm;
#pragma unroll
        for (int j = 0; j < 4; j++) {
            int cl = colBase + j * 16 + (l & 15);
            int o  = bn * 128 + cl - 2048;
            float bv = bias[bn * 128 + cl];
            float tr = trace[(o >> 6) * 4096 + (o & 63) * 65];
#pragma unroll
            for (int i = 0; i < 4; i++) {
                int s0 = rowBase + i * 16 + ((l >> 4) << 2);
                *(ushort4*)(Lt + cl * 136 + s0) =
                    pkbf4((acc[i][j][0] + bv) * tr, (acc[i][j][1] + bv) * tr,
                          (acc[i][j][2] + bv) * tr, (acc[i][j][3] + bv) * tr);
            }
        }
        __syncthreads();
#pragma unroll
        for (int p = 0; p < 8; ++p) {
            int dl  = (t >> 4) + p * 16;
            int sch = (t & 15) * 8;
            int o = bn * 128 + dl - 2048;
            int h = o >> 6, d = o & 63;
            s16x8 v = *(const s16x8*)(Lt + dl * 136 + sch);
            *(s16x8*)(Vt + (h * 64 + d) * S_LEN + bm * 128 + sch) = v;
        }
    }
}

// ---------------------------------------------------------------------------
// Kernel B: flash attention (UNCHANGED from R2/R5 88.3 µs version).
// DMA dbuf staging (zero staging regs), 1 barrier/kt, T12 in-register P,
// T5 setprio. LDS: 4 staging bufs x 16KB + epilogue reuse = 69632 B.
// ---------------------------------------------------------------------------
__global__ __launch_bounds__(512, 4) void attn(
    const unsigned short* __restrict__ Qb, const unsigned short* __restrict__ Kb,
    const unsigned short* __restrict__ Vt, float* __restrict__ out)
{
    __shared__ __align__(16) unsigned short sm[34816];   // 69632 B
    __shared__ float lArr[256];

    const int t = threadIdx.x;
    const int l = t & 63;
    const int w = t >> 6;            // 0..7
    const int g = w >> 2;            // kv half
    const int wg = w & 3;            // wave within group
    const int wq = w & 3;            // q sub-tile
    // XCD swizzle: xcd = bid%8 owns heads {2*xcd, 2*xcd+1}
    const int bid = blockIdx.x;
    const int xcd = bid & 7;
    const int j   = bid >> 3;        // 0..63
    const int h   = xcd * 2 + (j & 1);
    const int qblk = j >> 1;         // 0..31
    const int qbase = qblk * 128 + wq * 32;
    const int l31 = l & 31;
    const int lh  = l >> 5;
    const int swz = l31 & 7;         // read-side XOR (row&7)

    s16x8 qf[4];
#pragma unroll
    for (int ks = 0; ks < 4; ks++)
        qf[ks] = *(const s16x8*)(Qb + (h * S_LEN + qbase + l31) * 64 + ks * 16 + lh * 8);

    f32x16 O0 = (f32x16)0.f, O1 = (f32x16)0.f;
    float2 lpA; lpA.x = 0.f; lpA.y = 0.f;
    float2 lpB; lpB.x = 0.f; lpB.y = 0.f;

    // --- DMA staging addresses -------------------------------------------
    // Physical 16B chunk p = (wg*2+j)*64 + lane; row = p>>3, pc = p&7.
    // Logical chunk c = pc ^ (row&7)  (inverse-swizzled global source).
    // Wave instr j writes LDS linearly at base + (wg*2+j)*1024B + lane*16.
    const int p0 = (wg * 2 + 0) * 64 + l;
    const int p1 = (wg * 2 + 1) * 64 + l;
    const int r0_ = p0 >> 3, c0_ = (p0 & 7) ^ (r0_ & 7);
    const int r1_ = p1 >> 3, c1_ = (p1 & 7) ^ (r1_ & 7);
    const unsigned short* gk0 = Kb + (h * S_LEN + g * 2048 + r0_) * 64 + c0_ * 8;
    const unsigned short* gk1 = Kb + (h * S_LEN + g * 2048 + r1_) * 64 + c1_ * 8;
    const unsigned short* gv0 = Vt + (h * 64 + r0_) * S_LEN + g * 2048 + c0_ * 8;
    const unsigned short* gv1 = Vt + (h * 64 + r1_) * S_LEN + g * 2048 + c1_ * 8;

    // prologue: stage tile 0 into buf 0
    {
        unsigned short* kb_ = sm + g * 8192 + wg * 1024;
        async16(gk0, kb_);
        async16(gk1, kb_ + 512);
        async16(gv0, kb_ + 4096);
        async16(gv1, kb_ + 4096 + 512);
    }

    for (int kt = 0; kt < 32; ++kt) {
        __syncthreads();   // implicit vmcnt(0): buf[kt&1] DMA done everywhere;
                           // all waves finished reading buf[kt&1 ^ 1]
        const unsigned short* sb  = sm + ((kt & 1) * 2 + g) * 8192;
        const unsigned short* vbs = sb + 4096;

        // issue next tile's DMA into the other buffer (zero registers)
        if (kt < 31) {
            gk0 += 4096; gk1 += 4096; gv0 += 64; gv1 += 64;
            unsigned short* kb_ = sm + (((kt + 1) & 1) * 2 + g) * 8192 + wg * 1024;
            async16(gk0, kb_);
            async16(gk1, kb_ + 512);
            async16(gv0, kb_ + 4096);
            async16(gv1, kb_ + 4096 + 512);
        }

        // S^T[kv][q] = K x Q^T  (scores pre-scaled via Q); swizzled reads
        f32x16 S0 = (f32x16)0.f, S1 = (f32x16)0.f;
        __builtin_amdgcn_s_setprio(1);
#pragma unroll
        for (int ks = 0; ks < 4; ks++) {
            const int off = ((ks * 2 + lh) ^ swz) * 8;
            s16x8 a0 = *(const s16x8*)(sb + l31 * 64 + off);
            s16x8 a1 = *(const s16x8*)(sb + (32 + l31) * 64 + off);
            S0 = __builtin_amdgcn_mfma_f32_32x32x16_bf16(a0, qf[ks], S0, 0, 0, 0);
            S1 = __builtin_amdgcn_mfma_f32_32x32x16_bf16(a1, qf[ks], S1, 0, 0, 0);
        }
        __builtin_amdgcn_s_setprio(0);

#pragma unroll
        for (int i = 0; i < 16; i += 4) {
            float p0v = __builtin_amdgcn_exp2f(S0[i+0]); S0[i+0] = p0v; lpA.x += p0v;
            float p1v = __builtin_amdgcn_exp2f(S0[i+1]); S0[i+1] = p1v; lpA.y += p1v;
            float p2v = __builtin_amdgcn_exp2f(S0[i+2]); S0[i+2] = p2v; lpB.x += p2v;
            float p3v = __builtin_amdgcn_exp2f(S0[i+3]); S0[i+3] = p3v; lpB.y += p3v;
        }
#pragma unroll
        for (int i = 0; i < 16; i += 4) {
            float p0v = __builtin_amdgcn_exp2f(S1[i+0]); S1[i+0] = p0v; lpA.x += p0v;
            float p1v = __builtin_amdgcn_exp2f(S1[i+1]); S1[i+1] = p1v; lpA.y += p1v;
            float p2v = __builtin_amdgcn_exp2f(S1[i+2]); S1[i+2] = p2v; lpB.x += p2v;
            float p3v = __builtin_amdgcn_exp2f(S1[i+3]); S1[i+3] = p3v; lpB.y += p3v;
        }

        // T12: O^T[d][q] += V^T x P^T, P built in-register (R1-verified map).
        __builtin_amdgcn_s_setprio(1);
#define PVBLK(SX, BO, KS) do {                                               \
        unsigned pa0 = pku(SX[(BO)+0], SX[(BO)+1]);                          \
        unsigned pc0 = pku(SX[(BO)+4], SX[(BO)+5]);                          \
        unsigned pa1 = pku(SX[(BO)+2], SX[(BO)+3]);                          \
        unsigned pc1 = pku(SX[(BO)+6], SX[(BO)+7]);                          \
        auto r0 = __builtin_amdgcn_permlane32_swap(pa0, pc0, false, false);  \
        auto r1 = __builtin_amdgcn_permlane32_swap(pa1, pc1, false, false);  \
        union { s16x8 v; unsigned u[4]; } pb_;                               \
        pb_.u[0] = r0[0]; pb_.u[1] = r1[0]; pb_.u[2] = r0[1]; pb_.u[3] = r1[1]; \
        const int offv = (((KS) * 2 + lh) ^ swz) * 8;                        \
        s16x8 av0 = *(const s16x8*)(vbs + l31 * 64 + offv);                  \
        s16x8 av1 = *(const s16x8*)(vbs + (32 + l31) * 64 + offv);           \
        O0 = __builtin_amdgcn_mfma_f32_32x32x16_bf16(av0, pb_.v, O0, 0, 0, 0); \
        O1 = __builtin_amdgcn_mfma_f32_32x32x16_bf16(av1, pb_.v, O1, 0, 0, 0); \
    } while (0)
        PVBLK(S0, 0, 0);
        PVBLK(S0, 8, 1);
        PVBLK(S1, 0, 2);
        PVBLK(S1, 8, 3);
#undef PVBLK
        __builtin_amdgcn_s_setprio(0);
    }

    // per-wave l partial for q = qbase + l31
    float l_part = (lpA.x + lpA.y) + (lpB.x + lpB.y);
    float l_tot = l_part + __shfl_xor(l_part, 32);
    if (lh == 0) lArr[w * 32 + l31] = l_tot;

    __syncthreads();    // drain last PV's LDS reads before Lo overwrites sm

    // stash raw O^T (fp32) per wave: Lo[w][q 0..31][d 0..67(pad)]
    float* Lo = (float*)sm + w * 2176;
#pragma unroll
    for (int dt = 0; dt < 2; ++dt) {
        const f32x16& Ox = dt ? O1 : O0;
#pragma unroll
        for (int gq = 0; gq < 4; ++gq) {
            int d0 = dt * 32 + gq * 8 + lh * 4;
            float4 vv;
            vv.x = Ox[gq*4+0]; vv.y = Ox[gq*4+1]; vv.z = Ox[gq*4+2]; vv.w = Ox[gq*4+3];
            *(float4*)(Lo + l31 * 68 + d0) = vv;
        }
    }
    __syncthreads();

    // waves 0-3: combine the two kv-half partials, normalize, store
    if (w < 4) {
        const float* LoA = (float*)sm + w * 2176;
        const float* LoB = (float*)sm + (w + 4) * 2176;
#pragma unroll
        for (int it = 0; it < 8; ++it) {
            int ql = it * 4 + (l >> 4);
            float invl = 1.0f / (lArr[w * 32 + ql] + lArr[(w + 4) * 32 + ql]);
            float4 a = *(const float4*)(LoA + ql * 68 + (l & 15) * 4);
            float4 b = *(const float4*)(LoB + ql * 68 + (l & 15) * 4);
            float4 vv;
            vv.x = (a.x + b.x) * invl;
            vv.y = (a.y + b.y) * invl;
            vv.z = (a.z + b.z) * invl;
            vv.w = (a.w + b.w) * invl;
            *(float4*)(out + (qblk * 128 + w * 32 + ql) * 1024 + h * 64 + (l & 15) * 4) = vv;
        }
    }
}

extern "C" void kernel_launch(void* const* d_in, const int* in_sizes, int n_in,
                              void* d_out, int out_size, void* d_ws, size_t ws_size,
                              hipStream_t stream) {
    const float* X     = (const float*)d_in[0];   // [1,4096,1024]
    const float* W     = (const float*)d_in[1];   // [3072,1024]
    const float* bias  = (const float*)d_in[2];   // [3072]
    const float* trace = (const float*)d_in[3];   // [16,64,64]
    float* out = (float*)d_out;

    unsigned short* Qb = (unsigned short*)d_ws;            // 8 MiB [h][s][d] (pre-scaled by CEXP)
    unsigned short* Kb = Qb + 4194304;                     // 8 MiB [h][s][d]
    unsigned short* Vt = Kb + 4194304;                     // 8 MiB [h][d][s] (pre-scaled by trace diag)
    unsigned short* Xb = Vt + 4194304;                     // 8 MiB bf16 X
    unsigned short* Wb = Xb + 4194304;                     // 6 MiB bf16 W

    const size_t NEED_BF16 = (size_t)3 * 8388608 + 8388608 + 6291456;

    if (ws_size >= NEED_BF16) {
        cvt_bf16<<<3584, 256, 0, stream>>>(X, W, Xb, Wb);
        qkv_gemm_bf16<<<dim3(24, 32), 256, 0, stream>>>(Xb, Wb, bias, trace, Qb, Kb, Vt);
    } else {
        qkv_gemm_f32<<<dim3(24, 32), 256, 0, stream>>>(X, W, bias, trace, Qb, Kb, Vt);
    }
    attn<<<512, 512, 0, stream>>>(Qb, Kb, Vt, out);
}

// Round 7
// 195.360 us; speedup vs baseline: 1.4557x; 1.0273x over previous
//
#include <hip/hip_runtime.h>
#include <hip/hip_bf16.h>
#include <stdint.h>

#define S_LEN 4096

typedef short s16x8  __attribute__((ext_vector_type(8)));
typedef float f32x4  __attribute__((ext_vector_type(4)));
typedef float f32x16 __attribute__((ext_vector_type(16)));

// log2(e)/8 : folded into Q at QKV epilogue; attn does exp2(score) directly
#define CEXP 0.18033688011112042f

__device__ __forceinline__ unsigned short f2bf(float f) {
    union { float f; unsigned u; } v; v.f = f;
    unsigned r = v.u + 0x7fffu + ((v.u >> 16) & 1u);
    return (unsigned short)(r >> 16);
}

__device__ __forceinline__ ushort2 pkbf(float a, float b) {
    float2 f; f.x = a; f.y = b;
    __hip_bfloat162 h = __float22bfloat162_rn(f);
    union { __hip_bfloat162 h; ushort2 u; } cv; cv.h = h;
    return cv.u;
}

__device__ __forceinline__ ushort4 pkbf4(float x, float y, float z, float w) {
    ushort2 lo = pkbf(x, y), hi = pkbf(z, w);
    ushort4 r; r.x = lo.x; r.y = lo.y; r.z = hi.x; r.w = hi.y;
    return r;
}

__device__ __forceinline__ unsigned pku(float a, float b) {
    union { ushort2 s; unsigned u; } c; c.s = pkbf(a, b); return c.u;
}

typedef const __attribute__((address_space(1))) void* gas_t;
typedef __attribute__((address_space(3))) void* sas_t;

__device__ __forceinline__ void async16(const void* g, void* s) {
    __builtin_amdgcn_global_load_lds((gas_t)g, (sas_t)s, 16, 0, 0);
}

// ---------------------------------------------------------------------------
// fp32 -> bf16 convert for X (4194304) and W (3145728). 8 elems/thread.
// ---------------------------------------------------------------------------
__global__ __launch_bounds__(256) void cvt_bf16(
    const float* __restrict__ X, const float* __restrict__ W,
    unsigned short* __restrict__ Xb, unsigned short* __restrict__ Wb)
{
    const long NX = 4194304;
    long i = (long)(blockIdx.x * 256 + threadIdx.x) * 8;
    const float* src; unsigned short* dst; long off;
    if (i < NX) { src = X; dst = Xb; off = i; }
    else        { src = W; dst = Wb; off = i - NX; }
    float4 a = *(const float4*)(src + off);
    float4 b = *(const float4*)(src + off + 4);
    union { s16x8 v; ushort4 q[2]; } o;
    o.q[0] = pkbf4(a.x, a.y, a.z, a.w);
    o.q[1] = pkbf4(b.x, b.y, b.z, b.w);
    *(s16x8*)(dst + off) = o.v;
}

// ---------------------------------------------------------------------------
// Kernel A (primary): qkv = Xb @ Wb^T + b, bf16 in.
// R7: BK 64->32. dbuf staging shrinks to 2x16KB = 32KB; LDS block = 34816B
// (epilogue [128][136] dominates) -> 4 blocks/CU -> ALL 768 blocks resident
// (R6's 64KB dbuf capped at 2/CU: 512 + 256-block tail with half the chip
// idle - why dbuf only gained 6 µs). Keeps 1 barrier/kt (now 32 kts) AND
// cross-block latency hiding. Same total DMA bytes/MFMA count.
// Vectorized Q/K epilogue (R5-verified) unchanged. dim3(24,32) unchanged.
// ---------------------------------------------------------------------------
__global__ __launch_bounds__(256) void qkv_gemm_bf16(
    const unsigned short* __restrict__ Xb, const unsigned short* __restrict__ Wb,
    const float* __restrict__ bias, const float* __restrict__ trace,
    unsigned short* __restrict__ Qb, unsigned short* __restrict__ Kb,
    unsigned short* __restrict__ Vt)
{
    __shared__ __align__(16) unsigned short sm[17408];   // 34816 B
    // staging: buf b at sm + b*8192 shorts; A = [128][32], B = A + 4096

    const int t = threadIdx.x;
    const int l = t & 63;
    const int w = t >> 6;
    const int bm = blockIdx.y, bn = blockIdx.x;
    const int rowBase = (w >> 1) * 64;
    const int colBase = (w & 1) * 64;

    f32x4 acc[4][4];
#pragma unroll
    for (int i = 0; i < 4; i++)
#pragma unroll
        for (int j = 0; j < 4; j++) acc[i][j] = (f32x4)0.f;

    // staging map: 16B chunk p in [0,512): row = p>>2 (4 chunks per 32-short
    // row), chunk-col = p&3. Wave w, instr j in {0,1}: p = w*128 + j*64 + l.
    // LDS dst = sm + p*8 shorts = wave-uniform base + lane*16B (DMA rule).
    const int p0 = w * 128 + l;
    const int p1 = p0 + 64;
    const int ar0 = p0 >> 2, ac0 = (p0 & 3) * 8;
    const int ar1 = p1 >> 2, ac1 = (p1 & 3) * 8;

    // prologue: stage K-tile 0 into buf 0
    async16(Xb + (bm * 128 + ar0) * 1024 + ac0, sm + p0 * 8);
    async16(Xb + (bm * 128 + ar1) * 1024 + ac1, sm + p1 * 8);
    async16(Wb + (bn * 128 + ar0) * 1024 + ac0, sm + 4096 + p0 * 8);
    async16(Wb + (bn * 128 + ar1) * 1024 + ac1, sm + 4096 + p1 * 8);

    for (int kt = 0; kt < 32; ++kt) {
        __syncthreads();   // implicit vmcnt(0): buf[kt&1] DMA complete;
                           // all waves done reading buf[kt&1 ^ 1]
        const unsigned short* As = sm + (kt & 1) * 8192;
        const unsigned short* Bs = As + 4096;

        if (kt < 31) {
            const int k0 = (kt + 1) * 32;
            unsigned short* An = sm + ((kt + 1) & 1) * 8192;
            async16(Xb + (bm * 128 + ar0) * 1024 + k0 + ac0, An + p0 * 8);
            async16(Xb + (bm * 128 + ar1) * 1024 + k0 + ac1, An + p1 * 8);
            async16(Wb + (bn * 128 + ar0) * 1024 + k0 + ac0, An + 4096 + p0 * 8);
            async16(Wb + (bn * 128 + ar1) * 1024 + k0 + ac1, An + 4096 + p1 * 8);
        }

        s16x8 af[4], bf[4];
#pragma unroll
        for (int i = 0; i < 4; i++) {
            af[i] = *(const s16x8*)(As + (rowBase + i * 16 + (l & 15)) * 32 + (l >> 4) * 8);
            bf[i] = *(const s16x8*)(Bs + (colBase + i * 16 + (l & 15)) * 32 + (l >> 4) * 8);
        }
#pragma unroll
        for (int i = 0; i < 4; i++)
#pragma unroll
            for (int j = 0; j < 4; j++)
                acc[i][j] = __builtin_amdgcn_mfma_f32_16x16x32_bf16(af[i], bf[j], acc[i][j], 0, 0, 0);
    }

    __syncthreads();   // all compute reads done; sm free for epilogue reuse

    if (bn < 16) {
        // Q/K epilogue: LDS transpose -> vectorized 16B stores.
        unsigned short* Ls = sm;                  // [128 s][136 c]
        const int region = bn >> 3;               // 0 = Q (bn<8), 1 = K
        unsigned short* dst = region ? Kb : Qb;
        const float scl = region ? 1.0f : CEXP;
#pragma unroll
        for (int j = 0; j < 4; j++) {
            int cl = colBase + j * 16 + (l & 15);          // block-local col
            float bv = bias[bn * 128 + cl];
#pragma unroll
            for (int i = 0; i < 4; i++) {
                int s0 = rowBase + i * 16 + ((l >> 4) << 2);
#pragma unroll
                for (int r = 0; r < 4; r++)
                    Ls[(s0 + r) * 136 + cl] = f2bf((acc[i][j][r] + bv) * scl);
            }
        }
        __syncthreads();
#pragma unroll
        for (int p = 0; p < 8; ++p) {
            int tk = p * 256 + t;
            int s  = tk >> 4;                  // 0..127
            int ch = tk & 15;                  // 0..15 (8-col chunk)
            int gc = bn * 128 + ch * 8;
            int h  = (gc >> 6) & 15, d = gc & 63;
            s16x8 v = *(const s16x8*)(Ls + s * 136 + ch * 8);
            *(s16x8*)(dst + (h * S_LEN + bm * 128 + s) * 64 + d) = v;
        }
    } else {
        unsigned short* Lt = sm;              // 128 x 136
#pragma unroll
        for (int j = 0; j < 4; j++) {
            int cl = colBase + j * 16 + (l & 15);
            int o  = bn * 128 + cl - 2048;     // 0..1023 within V
            float bv = bias[bn * 128 + cl];
            float tr = trace[(o >> 6) * 4096 + (o & 63) * 65];
#pragma unroll
            for (int i = 0; i < 4; i++) {
                int s0 = rowBase + i * 16 + ((l >> 4) << 2);
                *(ushort4*)(Lt + cl * 136 + s0) =
                    pkbf4((acc[i][j][0] + bv) * tr, (acc[i][j][1] + bv) * tr,
                          (acc[i][j][2] + bv) * tr, (acc[i][j][3] + bv) * tr);
            }
        }
        __syncthreads();
#pragma unroll
        for (int p = 0; p < 8; ++p) {
            int dl  = (t >> 4) + p * 16;
            int sch = (t & 15) * 8;
            int o = bn * 128 + dl - 2048;
            int h = o >> 6, d = o & 63;
            s16x8 v = *(const s16x8*)(Lt + dl * 136 + sch);
            *(s16x8*)(Vt + (h * 64 + d) * S_LEN + bm * 128 + sch) = v;
        }
    }
}

// ---------------------------------------------------------------------------
// Kernel A (fallback, small ws): fp32-staged GEMM, same outputs (unchanged)
// ---------------------------------------------------------------------------
__global__ __launch_bounds__(256) void qkv_gemm_f32(
    const float* __restrict__ X, const float* __restrict__ W,
    const float* __restrict__ bias, const float* __restrict__ trace,
    unsigned short* __restrict__ Qb, unsigned short* __restrict__ Kb,
    unsigned short* __restrict__ Vt)
{
    __shared__ __align__(16) unsigned short sm[17408];
    unsigned short* As = sm;
    unsigned short* Bs = sm + 5120;

    const int t = threadIdx.x;
    const int l = t & 63;
    const int w = t >> 6;
    const int bm = blockIdx.y, bn = blockIdx.x;
    const int rowBase = (w >> 1) * 64;
    const int colBase = (w & 1) * 64;

    f32x4 acc[4][4];
#pragma unroll
    for (int i = 0; i < 4; i++)
#pragma unroll
        for (int j = 0; j < 4; j++) acc[i][j] = (f32x4)0.f;

    const int sr = t >> 3;
    const int sc = (t & 7) * 4;

    for (int kt = 0; kt < 32; ++kt) {
        const int k0 = kt * 32;
#pragma unroll
        for (int p = 0; p < 4; ++p) {
            int r = sr + p * 32;
            float4 xa = *(const float4*)(X + (bm * 128 + r) * 1024 + k0 + sc);
            float4 wb = *(const float4*)(W + (bn * 128 + r) * 1024 + k0 + sc);
            *(ushort4*)(As + r * 40 + sc) = pkbf4(xa.x, xa.y, xa.z, xa.w);
            *(ushort4*)(Bs + r * 40 + sc) = pkbf4(wb.x, wb.y, wb.z, wb.w);
        }
        __syncthreads();

        s16x8 af[4], bf[4];
#pragma unroll
        for (int i = 0; i < 4; i++) {
            af[i] = *(const s16x8*)(As + (rowBase + i * 16 + (l & 15)) * 40 + (l >> 4) * 8);
            bf[i] = *(const s16x8*)(Bs + (colBase + i * 16 + (l & 15)) * 40 + (l >> 4) * 8);
        }
#pragma unroll
        for (int i = 0; i < 4; i++)
#pragma unroll
            for (int j = 0; j < 4; j++)
                acc[i][j] = __builtin_amdgcn_mfma_f32_16x16x32_bf16(af[i], bf[j], acc[i][j], 0, 0, 0);
        __syncthreads();
    }

    if (bn < 16) {
#pragma unroll
        for (int j = 0; j < 4; j++) {
            int col = bn * 128 + colBase + j * 16 + (l & 15);
            float bv = bias[col];
            int region = col >> 10;
            int within = col & 1023;
            int h = within >> 6, d = within & 63;
            unsigned short* dst = (region == 0) ? Qb : Kb;
            float scl = (region == 0) ? CEXP : 1.0f;
#pragma unroll
            for (int i = 0; i < 4; i++) {
                int s0 = bm * 128 + rowBase + i * 16 + ((l >> 4) << 2);
#pragma unroll
                for (int r = 0; r < 4; r++)
                    dst[(h * S_LEN + s0 + r) * 64 + d] = f2bf((acc[i][j][r] + bv) * scl);
            }
        }
    } else {
        __syncthreads();
        unsigned short* Lt = sm;
#pragma unroll
        for (int j = 0; j < 4; j++) {
            int cl = colBase + j * 16 + (l & 15);
            int o  = bn * 128 + cl - 2048;
            float bv = bias[bn * 128 + cl];
            float tr = trace[(o >> 6) * 4096 + (o & 63) * 65];
#pragma unroll
            for (int i = 0; i < 4; i++) {
                int s0 = rowBase + i * 16 + ((l >> 4) << 2);
                *(ushort4*)(Lt + cl * 136 + s0) =
                    pkbf4((acc[i][j][0] + bv) * tr, (acc[i][j][1] + bv) * tr,
                          (acc[i][j][2] + bv) * tr, (acc[i][j][3] + bv) * tr);
            }
        }
        __syncthreads();
#pragma unroll
        for (int p = 0; p < 8; ++p) {
            int dl  = (t >> 4) + p * 16;
            int sch = (t & 15) * 8;
            int o = bn * 128 + dl - 2048;
            int h = o >> 6, d = o & 63;
            s16x8 v = *(const s16x8*)(Lt + dl * 136 + sch);
            *(s16x8*)(Vt + (h * 64 + d) * S_LEN + bm * 128 + sch) = v;
        }
    }
}

// ---------------------------------------------------------------------------
// Kernel B: flash attention (UNCHANGED from R2/R5/R6 88.8 µs version).
// DMA dbuf staging (zero staging regs), 1 barrier/kt, T12 in-register P,
// T5 setprio. LDS: 4 staging bufs x 16KB + epilogue reuse = 69632 B.
// ---------------------------------------------------------------------------
__global__ __launch_bounds__(512, 4) void attn(
    const unsigned short* __restrict__ Qb, const unsigned short* __restrict__ Kb,
    const unsigned short* __restrict__ Vt, float* __restrict__ out)
{
    __shared__ __align__(16) unsigned short sm[34816];   // 69632 B
    __shared__ float lArr[256];

    const int t = threadIdx.x;
    const int l = t & 63;
    const int w = t >> 6;            // 0..7
    const int g = w >> 2;            // kv half
    const int wg = w & 3;            // wave within group
    const int wq = w & 3;            // q sub-tile
    // XCD swizzle: xcd = bid%8 owns heads {2*xcd, 2*xcd+1}
    const int bid = blockIdx.x;
    const int xcd = bid & 7;
    const int j   = bid >> 3;        // 0..63
    const int h   = xcd * 2 + (j & 1);
    const int qblk = j >> 1;         // 0..31
    const int qbase = qblk * 128 + wq * 32;
    const int l31 = l & 31;
    const int lh  = l >> 5;
    const int swz = l31 & 7;         // read-side XOR (row&7)

    s16x8 qf[4];
#pragma unroll
    for (int ks = 0; ks < 4; ks++)
        qf[ks] = *(const s16x8*)(Qb + (h * S_LEN + qbase + l31) * 64 + ks * 16 + lh * 8);

    f32x16 O0 = (f32x16)0.f, O1 = (f32x16)0.f;
    float2 lpA; lpA.x = 0.f; lpA.y = 0.f;
    float2 lpB; lpB.x = 0.f; lpB.y = 0.f;

    // --- DMA staging addresses -------------------------------------------
    // Physical 16B chunk p = (wg*2+j)*64 + lane; row = p>>3, pc = p&7.
    // Logical chunk c = pc ^ (row&7)  (inverse-swizzled global source).
    // Wave instr j writes LDS linearly at base + (wg*2+j)*1024B + lane*16.
    const int p0 = (wg * 2 + 0) * 64 + l;
    const int p1 = (wg * 2 + 1) * 64 + l;
    const int r0_ = p0 >> 3, c0_ = (p0 & 7) ^ (r0_ & 7);
    const int r1_ = p1 >> 3, c1_ = (p1 & 7) ^ (r1_ & 7);
    const unsigned short* gk0 = Kb + (h * S_LEN + g * 2048 + r0_) * 64 + c0_ * 8;
    const unsigned short* gk1 = Kb + (h * S_LEN + g * 2048 + r1_) * 64 + c1_ * 8;
    const unsigned short* gv0 = Vt + (h * 64 + r0_) * S_LEN + g * 2048 + c0_ * 8;
    const unsigned short* gv1 = Vt + (h * 64 + r1_) * S_LEN + g * 2048 + c1_ * 8;

    // prologue: stage tile 0 into buf 0
    {
        unsigned short* kb_ = sm + g * 8192 + wg * 1024;
        async16(gk0, kb_);
        async16(gk1, kb_ + 512);
        async16(gv0, kb_ + 4096);
        async16(gv1, kb_ + 4096 + 512);
    }

    for (int kt = 0; kt < 32; ++kt) {
        __syncthreads();   // implicit vmcnt(0): buf[kt&1] DMA done everywhere;
                           // all waves finished reading buf[kt&1 ^ 1]
        const unsigned short* sb  = sm + ((kt & 1) * 2 + g) * 8192;
        const unsigned short* vbs = sb + 4096;

        // issue next tile's DMA into the other buffer (zero registers)
        if (kt < 31) {
            gk0 += 4096; gk1 += 4096; gv0 += 64; gv1 += 64;
            unsigned short* kb_ = sm + (((kt + 1) & 1) * 2 + g) * 8192 + wg * 1024;
            async16(gk0, kb_);
            async16(gk1, kb_ + 512);
            async16(gv0, kb_ + 4096);
            async16(gv1, kb_ + 4096 + 512);
        }

        // S^T[kv][q] = K x Q^T  (scores pre-scaled via Q); swizzled reads
        f32x16 S0 = (f32x16)0.f, S1 = (f32x16)0.f;
        __builtin_amdgcn_s_setprio(1);
#pragma unroll
        for (int ks = 0; ks < 4; ks++) {
            const int off = ((ks * 2 + lh) ^ swz) * 8;
            s16x8 a0 = *(const s16x8*)(sb + l31 * 64 + off);
            s16x8 a1 = *(const s16x8*)(sb + (32 + l31) * 64 + off);
            S0 = __builtin_amdgcn_mfma_f32_32x32x16_bf16(a0, qf[ks], S0, 0, 0, 0);
            S1 = __builtin_amdgcn_mfma_f32_32x32x16_bf16(a1, qf[ks], S1, 0, 0, 0);
        }
        __builtin_amdgcn_s_setprio(0);

#pragma unroll
        for (int i = 0; i < 16; i += 4) {
            float p0v = __builtin_amdgcn_exp2f(S0[i+0]); S0[i+0] = p0v; lpA.x += p0v;
            float p1v = __builtin_amdgcn_exp2f(S0[i+1]); S0[i+1] = p1v; lpA.y += p1v;
            float p2v = __builtin_amdgcn_exp2f(S0[i+2]); S0[i+2] = p2v; lpB.x += p2v;
            float p3v = __builtin_amdgcn_exp2f(S0[i+3]); S0[i+3] = p3v; lpB.y += p3v;
        }
#pragma unroll
        for (int i = 0; i < 16; i += 4) {
            float p0v = __builtin_amdgcn_exp2f(S1[i+0]); S1[i+0] = p0v; lpA.x += p0v;
            float p1v = __builtin_amdgcn_exp2f(S1[i+1]); S1[i+1] = p1v; lpA.y += p1v;
            float p2v = __builtin_amdgcn_exp2f(S1[i+2]); S1[i+2] = p2v; lpB.x += p2v;
            float p3v = __builtin_amdgcn_exp2f(S1[i+3]); S1[i+3] = p3v; lpB.y += p3v;
        }

        // T12: O^T[d][q] += V^T x P^T, P built in-register (R1-verified map).
        __builtin_amdgcn_s_setprio(1);
#define PVBLK(SX, BO, KS) do {                                               \
        unsigned pa0 = pku(SX[(BO)+0], SX[(BO)+1]);                          \
        unsigned pc0 = pku(SX[(BO)+4], SX[(BO)+5]);                          \
        unsigned pa1 = pku(SX[(BO)+2], SX[(BO)+3]);                          \
        unsigned pc1 = pku(SX[(BO)+6], SX[(BO)+7]);                          \
        auto r0 = __builtin_amdgcn_permlane32_swap(pa0, pc0, false, false);  \
        auto r1 = __builtin_amdgcn_permlane32_swap(pa1, pc1, false, false);  \
        union { s16x8 v; unsigned u[4]; } pb_;                               \
        pb_.u[0] = r0[0]; pb_.u[1] = r1[0]; pb_.u[2] = r0[1]; pb_.u[3] = r1[1]; \
        const int offv = (((KS) * 2 + lh) ^ swz) * 8;                        \
        s16x8 av0 = *(const s16x8*)(vbs + l31 * 64 + offv);                  \
        s16x8 av1 = *(const s16x8*)(vbs + (32 + l31) * 64 + offv);           \
        O0 = __builtin_amdgcn_mfma_f32_32x32x16_bf16(av0, pb_.v, O0, 0, 0, 0); \
        O1 = __builtin_amdgcn_mfma_f32_32x32x16_bf16(av1, pb_.v, O1, 0, 0, 0); \
    } while (0)
        PVBLK(S0, 0, 0);
        PVBLK(S0, 8, 1);
        PVBLK(S1, 0, 2);
        PVBLK(S1, 8, 3);
#undef PVBLK
        __builtin_amdgcn_s_setprio(0);
    }

    // per-wave l partial for q = qbase + l31
    float l_part = (lpA.x + lpA.y) + (lpB.x + lpB.y);
    float l_tot = l_part + __shfl_xor(l_part, 32);
    if (lh == 0) lArr[w * 32 + l31] = l_tot;

    __syncthreads();    // drain last PV's LDS reads before Lo overwrites sm

    // stash raw O^T (fp32) per wave: Lo[w][q 0..31][d 0..67(pad)]
    float* Lo = (float*)sm + w * 2176;
#pragma unroll
    for (int dt = 0; dt < 2; ++dt) {
        const f32x16& Ox = dt ? O1 : O0;
#pragma unroll
        for (int gq = 0; gq < 4; ++gq) {
            int d0 = dt * 32 + gq * 8 + lh * 4;
            float4 vv;
            vv.x = Ox[gq*4+0]; vv.y = Ox[gq*4+1]; vv.z = Ox[gq*4+2]; vv.w = Ox[gq*4+3];
            *(float4*)(Lo + l31 * 68 + d0) = vv;
        }
    }
    __syncthreads();

    // waves 0-3: combine the two kv-half partials, normalize, store
    if (w < 4) {
        const float* LoA = (float*)sm + w * 2176;
        const float* LoB = (float*)sm + (w + 4) * 2176;
#pragma unroll
        for (int it = 0; it < 8; ++it) {
            int ql = it * 4 + (l >> 4);
            float invl = 1.0f / (lArr[w * 32 + ql] + lArr[(w + 4) * 32 + ql]);
            float4 a = *(const float4*)(LoA + ql * 68 + (l & 15) * 4);
            float4 b = *(const float4*)(LoB + ql * 68 + (l & 15) * 4);
            float4 vv;
            vv.x = (a.x + b.x) * invl;
            vv.y = (a.y + b.y) * invl;
            vv.z = (a.z + b.z) * invl;
            vv.w = (a.w + b.w) * invl;
            *(float4*)(out + (qblk * 128 + w * 32 + ql) * 1024 + h * 64 + (l & 15) * 4) = vv;
        }
    }
}

extern "C" void kernel_launch(void* const* d_in, const int* in_sizes, int n_in,
                              void* d_out, int out_size, void* d_ws, size_t ws_size,
                              hipStream_t stream) {
    const float* X     = (const float*)d_in[0];   // [1,4096,1024]
    const float* W     = (const float*)d_in[1];   // [3072,1024]
    const float* bias  = (const float*)d_in[2];   // [3072]
    const float* trace = (const float*)d_in[3];   // [16,64,64]
    float* out = (float*)d_out;

    unsigned short* Qb = (unsigned short*)d_ws;            // 8 MiB [h][s][d] (pre-scaled by CEXP)
    unsigned short* Kb = Qb + 4194304;                     // 8 MiB [h][s][d]
    unsigned short* Vt = Kb + 4194304;                     // 8 MiB [h][d][s] (pre-scaled by trace diag)
    unsigned short* Xb = Vt + 4194304;                     // 8 MiB bf16 X
    unsigned short* Wb = Xb + 4194304;                     // 6 MiB bf16 W

    const size_t NEED_BF16 = (size_t)3 * 8388608 + 8388608 + 6291456;

    if (ws_size >= NEED_BF16) {
        cvt_bf16<<<3584, 256, 0, stream>>>(X, W, Xb, Wb);
        qkv_gemm_bf16<<<dim3(24, 32), 256, 0, stream>>>(Xb, Wb, bias, trace, Qb, Kb, Vt);
    } else {
        qkv_gemm_f32<<<dim3(24, 32), 256, 0, stream>>>(X, W, bias, trace, Qb, Kb, Vt);
    }
    attn<<<512, 512, 0, stream>>>(Qb, Kb, Vt, out);
}